// Round 9
// baseline (133.187 us; speedup 1.0000x reference)
//
#include <hip/hip_runtime.h>
#include <math.h>

#define D 2048
#define F 256
#define ALPHA 0.005f
#define STOPTHR 0.005f
#define EPSV 1e-16f

// fast path: 64 blocks x 1024 threads, 32 rows/block, bf16 K in 128KB dynamic LDS
#define NBLK_L 64
#define RPB_L 32
// fallback path (r2-proven): 256 blocks x 256 threads, 8 rows/block, f32 K
#define NBLK_F 256
#define RPB_F 8

typedef __bf16 bf16x8 __attribute__((ext_vector_type(8)));
typedef float f32x4 __attribute__((ext_vector_type(4)));
typedef unsigned short u16x8 __attribute__((ext_vector_type(8)));

__device__ __forceinline__ unsigned short f2bf(float f) {
    unsigned u = __float_as_uint(f);
    unsigned r = (u + 0x7FFFu + ((u >> 16) & 1u)) >> 16;  // RNE
    return (unsigned short)r;
}
__device__ __forceinline__ float bf2f(unsigned short b) {
    return __uint_as_float(((unsigned)b) << 16);
}
__device__ __forceinline__ float bflo(unsigned w) { return __uint_as_float(w << 16); }
__device__ __forceinline__ float bfhi(unsigned w) { return __uint_as_float(w & 0xFFFF0000u); }

// ---- flat central grid barrier (r0-r8 proven) — used by fallback ----
__device__ __forceinline__ void gbarN(unsigned* cnt, unsigned* gen, unsigned& lg, int N) {
    __syncthreads();
    if (threadIdx.x == 0) {
        unsigned g = lg;
        unsigned a = __hip_atomic_fetch_add(cnt, 1u, __ATOMIC_ACQ_REL, __HIP_MEMORY_SCOPE_AGENT);
        if (a == (unsigned)(N - 1)) {
            __hip_atomic_store(cnt, 0u, __ATOMIC_RELAXED, __HIP_MEMORY_SCOPE_AGENT);
            __hip_atomic_store(gen, g + 1u, __ATOMIC_RELEASE, __HIP_MEMORY_SCOPE_AGENT);
        } else {
            while ((int)(__hip_atomic_load(gen, __ATOMIC_ACQUIRE, __HIP_MEMORY_SCOPE_AGENT) - (g + 1u)) < 0) {}
        }
    }
    __syncthreads();
    lg++;
}

// ---- 2-level tree barrier: 8 leaves x 8 blocks + 8-way root (arrival chain 64->16) ----
// Ordering: block stores -> leaf RMW(acq_rel) -> leaf-last's root RMW(acq_rel) ->
// gen store(release); pollers acquire gen. Every link reads the prior RMW => transitive
// happens-before, same release-sequence mechanism as the proven flat gbar.
__device__ __forceinline__ void gbar_tree(unsigned* leaf, unsigned* root, unsigned* gen,
                                          unsigned& lg) {
    __syncthreads();
    if (threadIdx.x == 0) {
        unsigned g = lg;
        int li = (blockIdx.x >> 3) & 7;  // blocks 0-7 -> leaf 0, 8-15 -> leaf 1, ...
        unsigned a = __hip_atomic_fetch_add(&leaf[li * 32], 1u, __ATOMIC_ACQ_REL,
                                            __HIP_MEMORY_SCOPE_AGENT);
        if (a == 7u) {
            __hip_atomic_store(&leaf[li * 32], 0u, __ATOMIC_RELAXED, __HIP_MEMORY_SCOPE_AGENT);
            unsigned b = __hip_atomic_fetch_add(root, 1u, __ATOMIC_ACQ_REL,
                                                __HIP_MEMORY_SCOPE_AGENT);
            if (b == 7u) {
                __hip_atomic_store(root, 0u, __ATOMIC_RELAXED, __HIP_MEMORY_SCOPE_AGENT);
                __hip_atomic_store(gen, g + 1u, __ATOMIC_RELEASE, __HIP_MEMORY_SCOPE_AGENT);
            } else {
                while ((int)(__hip_atomic_load(gen, __ATOMIC_ACQUIRE,
                                               __HIP_MEMORY_SCOPE_AGENT) - (g + 1u)) < 0) {}
            }
        } else {
            while ((int)(__hip_atomic_load(gen, __ATOMIC_ACQUIRE,
                                           __HIP_MEMORY_SCOPE_AGENT) - (g + 1u)) < 0) {}
        }
    }
    __syncthreads();
    lg++;
}

// ---------------- row stats + plain-bf16 cast + flag/accum init ----------------
__global__ void rowstats_kernel(const float* __restrict__ theta,
                                const float* __restrict__ emb,
                                float* __restrict__ sq, float* __restrict__ nrm,
                                unsigned short* __restrict__ Yth,
                                unsigned short* __restrict__ Yem,
                                float* __restrict__ err_buf, float* __restrict__ S_buf,
                                float* __restrict__ kl_buf,
                                unsigned* __restrict__ bar_cnt, unsigned* __restrict__ bar_gen,
                                unsigned* __restrict__ bar_leaf, unsigned* __restrict__ bar_root) {
    if (blockIdx.x == 0) {
        int t0 = threadIdx.x;
        if (t0 < 10) err_buf[t0] = 0.0f;
        else if (t0 == 10) S_buf[0] = 0.0f;
        else if (t0 == 11) kl_buf[0] = 0.0f;
        else if (t0 == 12) *bar_cnt = 0u;
        else if (t0 == 13) *bar_gen = 0u;
        else if (t0 == 14) *bar_root = 0u;
        else if (t0 >= 16 && t0 < 24) bar_leaf[(t0 - 16) * 32] = 0u;
    }
    int row = blockIdx.x;
    int t = threadIdx.x;  // 256 threads == F
    float tv = theta[row * F + t];
    float ev = emb[row * F + t];

    Yth[row * F + t] = f2bf(tv);
    Yem[row * F + t] = f2bf(ev);

    float s1 = tv * tv, s2 = ev * ev;
    for (int off = 32; off; off >>= 1) {
        s1 += __shfl_down(s1, off, 64);
        s2 += __shfl_down(s2, off, 64);
    }
    __shared__ float w1[4], w2[4];
    int wid = t >> 6;
    if ((t & 63) == 0) { w1[wid] = s1; w2[wid] = s2; }
    __syncthreads();
    if (t == 0) {
        sq[row]  = w1[0] + w1[1] + w1[2] + w1[3];
        nrm[row] = sqrtf(w2[0] + w2[1] + w2[2] + w2[3]);
    }
}

// ---------------- Gram via bf16 MFMA, K=256 plain bf16 (r8-proven, frozen) ----------------
#define GBK 64
#define GPAD 72

__global__ __launch_bounds__(256) void gram_mfma_kernel(
    const unsigned short* __restrict__ Yth, const unsigned short* __restrict__ Yem,
    const float* __restrict__ sq, const float* __restrict__ nrm,
    float* __restrict__ Kg, float* __restrict__ Pc) {
    int z = blockIdx.z;
    const unsigned short* Y = z ? Yem : Yth;
    int brow = blockIdx.y * 128;
    int bcol = blockIdx.x * 128;
    __shared__ __align__(16) unsigned short PA[128 * GPAD];
    __shared__ __align__(16) unsigned short PB[128 * GPAD];
    int tid = threadIdx.x;
    int wid = tid >> 6, lane = tid & 63;
    int wr = wid >> 1, wc = wid & 1;
    int lr = lane & 15;
    int lk = (lane >> 4) * 8;

    f32x4 acc[4][4] = {};

    for (int k0 = 0; k0 < F; k0 += GBK) {
        __syncthreads();
#pragma unroll
        for (int q = 0; q < 4; q++) {
            int c = tid + q * 256;
            int rw = c >> 3, ch = (c & 7) * 8;
            *(float4*)&PA[rw * GPAD + ch] =
                *(const float4*)&Y[(size_t)(brow + rw) * F + k0 + ch];
            *(float4*)&PB[rw * GPAD + ch] =
                *(const float4*)&Y[(size_t)(bcol + rw) * F + k0 + ch];
        }
        __syncthreads();
#pragma unroll
        for (int ks = 0; ks < 2; ks++) {
            bf16x8 af[4], bff[4];
#pragma unroll
            for (int m = 0; m < 4; m++)
                af[m] = *(const bf16x8*)&PA[(wr * 64 + m * 16 + lr) * GPAD + ks * 32 + lk];
#pragma unroll
            for (int n = 0; n < 4; n++)
                bff[n] = *(const bf16x8*)&PB[(wc * 64 + n * 16 + lr) * GPAD + ks * 32 + lk];
#pragma unroll
            for (int m = 0; m < 4; m++)
#pragma unroll
                for (int n = 0; n < 4; n++)
                    acc[m][n] = __builtin_amdgcn_mfma_f32_16x16x32_bf16(
                        af[m], bff[n], acc[m][n], 0, 0, 0);
        }
    }

    int ib = brow + wr * 64;
    int jb = bcol + wc * 64;
    int rr = (lane >> 4) * 4;
    if (z == 0) {
        float sqi[4][4];
#pragma unroll
        for (int m = 0; m < 4; m++)
#pragma unroll
            for (int q = 0; q < 4; q++) sqi[m][q] = sq[ib + m * 16 + rr + q];
#pragma unroll
        for (int n = 0; n < 4; n++) {
            int j = jb + n * 16 + lr;
            float sqj = sq[j];
#pragma unroll
            for (int m = 0; m < 4; m++)
#pragma unroll
                for (int q = 0; q < 4; q++) {
                    int i = ib + m * 16 + rr + q;
                    float cc = fmaxf(sqi[m][q] + sqj - 2.0f * acc[m][n][q], 0.0f);
                    Kg[(size_t)i * D + j] = __expf(-ALPHA * cc);
                }
        }
    } else {
        float nri[4][4];
#pragma unroll
        for (int m = 0; m < 4; m++)
#pragma unroll
            for (int q = 0; q < 4; q++) nri[m][q] = nrm[ib + m * 16 + rr + q];
#pragma unroll
        for (int n = 0; n < 4; n++) {
            int j = jb + n * 16 + lr;
            float nrj = nrm[j];
#pragma unroll
            for (int m = 0; m < 4; m++)
#pragma unroll
                for (int q = 0; q < 4; q++) {
                    int i = ib + m * 16 + rr + q;
                    Pc[(size_t)i * D + j] = acc[m][n][q] / (nri[m][q] * nrj + EPSV);
                }
        }
    }
}

// ========== FAST PATH: 64 blocks x 1024 threads, 32 rows/block, bf16 K, tree barrier ==========
__global__ __launch_bounds__(1024) void sinkhorn_loop_kernel(
    const float* __restrict__ Kg, const float* __restrict__ Pc,
    float* __restrict__ rsum,
    float* __restrict__ uslab, float* __restrict__ vslab,
    float* __restrict__ err_buf, float* __restrict__ S_buf,
    unsigned* __restrict__ bar_leaf, unsigned* __restrict__ bar_root,
    unsigned* __restrict__ bar_gen) {
    extern __shared__ unsigned short Krow_bf[];  // RPB_L * D bf16 = 128 KB dynamic
    __shared__ float vbuf[D], ubuf[D];           // 16 KB static
    __shared__ float redw[16];                   // per-wave scratch for block reduce
    int tid = threadIdx.x;
    int blk = blockIdx.x;
    int r = tid >> 5;        // 0..31
    int lane = tid & 31;
    int row = blk * RPB_L + r;
    unsigned lg = 0;

    // stage 32 K-rows f32 -> bf16 LDS
    {
        const float4* src = (const float4*)(Kg + (size_t)blk * RPB_L * D);
        for (int i = tid; i < RPB_L * D / 8; i += 1024) {
            float4 a = src[i * 2], b = src[i * 2 + 1];
            u16x8 w;
            w[0] = f2bf(a.x); w[1] = f2bf(a.y); w[2] = f2bf(a.z); w[3] = f2bf(a.w);
            w[4] = f2bf(b.x); w[5] = f2bf(b.y); w[6] = f2bf(b.z); w[7] = f2bf(b.w);
            *(u16x8*)&Krow_bf[i * 8] = w;
        }
    }
    // rsum of Pc for this block's 32 rows (consumed by kl_kernel via launch boundary)
    {
        const float4* p4 = (const float4*)(Pc + (size_t)row * D);
        float s = 0.0f;
        for (int k = lane; k < D / 4; k += 32) {
            float4 v = p4[k];
            s += (v.x + v.y) + (v.z + v.w);
        }
#pragma unroll
        for (int off = 16; off; off >>= 1) s += __shfl_xor(s, off, 32);
        if (lane == 0) rsum[row] = s;
    }
    __syncthreads();

    const float bval = 1.0f / (float)D;
    const float aval = 1.0f / (float)D;
    const unsigned short* Kr = &Krow_bf[r * D];

    // Ku for u0 = ones: row sum (from bf16)
    float p = 0.0f;
    for (int k8 = lane; k8 < D / 8; k8 += 32) {
        uint4 kw = *(const uint4*)&Kr[k8 * 8];
        p += bflo(kw.x) + bfhi(kw.x) + bflo(kw.y) + bfhi(kw.y) +
             bflo(kw.z) + bfhi(kw.z) + bflo(kw.w) + bfhi(kw.w);
    }
#pragma unroll
    for (int off = 16; off; off >>= 1) p += __shfl_xor(p, off, 32);
    float Ku = p;

    const float4* vsl4 = (const float4*)vslab;
    const float4* usl4 = (const float4*)uslab;
    float4* vb4w = (float4*)vbuf;
    float4* ub4w = (float4*)ubuf;
    const float4* vb4 = (const float4*)vbuf;
    const float4* ub4 = (const float4*)ubuf;

    float err = 1.0f;
    int cpt = 0;
    float v_r = 0.0f, u_r = 0.0f;
    while (err > STOPTHR && cpt < 500) {
        v_r = bval / (Ku + EPSV);
        if (lane == 0) vslab[row] = v_r;
        gbar_tree(bar_leaf, bar_root, bar_gen, lg);
        if (tid < D / 4) vb4w[tid] = vsl4[tid];  // bounce v -> dense LDS
        __syncthreads();
        p = 0.0f;
        for (int k8 = lane; k8 < D / 8; k8 += 32) {
            uint4 kw = *(const uint4*)&Kr[k8 * 8];
            float4 v0 = vb4[k8 * 2], v1 = vb4[k8 * 2 + 1];
            p = fmaf(bflo(kw.x), v0.x, p); p = fmaf(bfhi(kw.x), v0.y, p);
            p = fmaf(bflo(kw.y), v0.z, p); p = fmaf(bfhi(kw.y), v0.w, p);
            p = fmaf(bflo(kw.z), v1.x, p); p = fmaf(bfhi(kw.z), v1.y, p);
            p = fmaf(bflo(kw.w), v1.z, p); p = fmaf(bfhi(kw.w), v1.w, p);
        }
#pragma unroll
        for (int off = 16; off; off >>= 1) p += __shfl_xor(p, off, 32);
        u_r = aval / (p + EPSV);
        if (lane == 0) uslab[row] = u_r;
        gbar_tree(bar_leaf, bar_root, bar_gen, lg);
        if (tid < D / 4) ub4w[tid] = usl4[tid];  // bounce u -> dense LDS
        __syncthreads();
        p = 0.0f;
        for (int k8 = lane; k8 < D / 8; k8 += 32) {
            uint4 kw = *(const uint4*)&Kr[k8 * 8];
            float4 u0 = ub4[k8 * 2], u1 = ub4[k8 * 2 + 1];
            p = fmaf(bflo(kw.x), u0.x, p); p = fmaf(bfhi(kw.x), u0.y, p);
            p = fmaf(bflo(kw.y), u0.z, p); p = fmaf(bfhi(kw.y), u0.w, p);
            p = fmaf(bflo(kw.z), u1.x, p); p = fmaf(bfhi(kw.z), u1.y, p);
            p = fmaf(bflo(kw.w), u1.z, p); p = fmaf(bfhi(kw.w), u1.w, p);
        }
#pragma unroll
        for (int off = 16; off; off >>= 1) p += __shfl_xor(p, off, 32);
        Ku = p;
        cpt++;
        if (cpt % 50 == 1) {
            int chk = cpt / 50;  // 0..9
            float e = fabsf(v_r * Ku - bval);   // uniform across the row's 32 lanes
            e += __shfl_xor(e, 32, 64);         // pair the wave's two rows
            if ((tid & 63) == 0) redw[tid >> 6] = e;
            __syncthreads();
            if (tid == 0) {                      // ONE atomic per block
                float s = 0.0f;
#pragma unroll
                for (int i = 0; i < 16; i++) s += redw[i];
                atomicAdd(&err_buf[chk], s);
            }
            gbar_tree(bar_leaf, bar_root, bar_gen, lg);
            err = err_buf[chk];
        }
    }

    // ---- S = sum(max(u_i K_ij v_j, 1e-6)); consumed by kl_kernel (launch boundary) ----
    float pS = 0.0f;
    for (int k8 = lane; k8 < D / 8; k8 += 32) {
        uint4 kw = *(const uint4*)&Kr[k8 * 8];
        float4 v0 = vb4[k8 * 2], v1 = vb4[k8 * 2 + 1];
        pS += fmaxf(u_r * bflo(kw.x) * v0.x, 1e-6f) + fmaxf(u_r * bfhi(kw.x) * v0.y, 1e-6f) +
              fmaxf(u_r * bflo(kw.y) * v0.z, 1e-6f) + fmaxf(u_r * bfhi(kw.y) * v0.w, 1e-6f) +
              fmaxf(u_r * bflo(kw.z) * v1.x, 1e-6f) + fmaxf(u_r * bfhi(kw.z) * v1.y, 1e-6f) +
              fmaxf(u_r * bflo(kw.w) * v1.z, 1e-6f) + fmaxf(u_r * bfhi(kw.w) * v1.w, 1e-6f);
    }
#pragma unroll
    for (int off = 16; off; off >>= 1) pS += __shfl_xor(pS, off, 32);
    pS += __shfl_xor(pS, 32, 64);
    if ((tid & 63) == 0) redw[tid >> 6] = pS;
    __syncthreads();
    if (tid == 0) {
        float s = 0.0f;
#pragma unroll
        for (int i = 0; i < 16; i++) s += redw[i];
        atomicAdd(S_buf, s);
    }
}

// ========== FAST PATH tail: KL on full grid (256 blocks), out += via atomicAdd ==========
__global__ __launch_bounds__(256) void kl_kernel(
    const float* __restrict__ Kg, const float* __restrict__ Pc,
    const float* __restrict__ rsum,
    const float* __restrict__ uslab, const float* __restrict__ vslab,
    const float* __restrict__ S_buf,
    float* __restrict__ out) {
    __shared__ float vbuf[D], ubuf[D];  // 16 KB
    int tid = threadIdx.x;
    int blk = blockIdx.x;
    int r = tid >> 5;
    int lane = tid & 31;
    int row = blk * 8 + r;

    {
        const float4* vs4 = (const float4*)vslab;
        const float4* us4 = (const float4*)uslab;
        for (int i = tid; i < D / 4; i += 256) {
            ((float4*)vbuf)[i] = vs4[i];
            ((float4*)ubuf)[i] = us4[i];
        }
    }
    __syncthreads();

    float logS = __logf(S_buf[0]);
    float u_r = ubuf[row];
    float invr_i = 1.0f / rsum[row];
    float pkl = 0.0f;
    const float4* a4  = (const float4*)(Kg + (size_t)row * D);
    const float4* pc4 = (const float4*)(Pc + (size_t)row * D);
    const float4* rs4 = (const float4*)rsum;
    const float4* vb4 = (const float4*)vbuf;
    for (int k = lane; k < D / 4; k += 32) {
        float4 a = a4[k];
        float4 b = vb4[k];
        float4 pc = pc4[k];
        float4 rs = rs4[k];
        float P0 = pc.x * 0.5f * (invr_i + 1.0f / rs.x);
        float P1 = pc.y * 0.5f * (invr_i + 1.0f / rs.y);
        float P2 = pc.z * 0.5f * (invr_i + 1.0f / rs.z);
        float P3 = pc.w * 0.5f * (invr_i + 1.0f / rs.w);
        float q0 = fmaxf(u_r * a.x * b.x, 1e-6f);
        float q1 = fmaxf(u_r * a.y * b.y, 1e-6f);
        float q2 = fmaxf(u_r * a.z * b.z, 1e-6f);
        float q3 = fmaxf(u_r * a.w * b.w, 1e-6f);
        pkl += P0 * (__logf(P0) - __logf(q0) + logS);
        pkl += P1 * (__logf(P1) - __logf(q1) + logS);
        pkl += P2 * (__logf(P2) - __logf(q2) + logS);
        pkl += P3 * (__logf(P3) - __logf(q3) + logS);
    }
#pragma unroll
    for (int off = 16; off; off >>= 1) pkl += __shfl_xor(pkl, off, 32);
    pkl += __shfl_xor(pkl, 32, 64);
    if ((tid & 63) == 0) atomicAdd(out, pkl);  // out memset to 0 by harness per replay
}

// ========== FALLBACK: r2-proven monolithic sinkhorn (256 blocks, flat gbar) ==========
__global__ __launch_bounds__(256) void sinkhorn_kernel(
    const float* __restrict__ Kg, const float* __restrict__ Pc,
    float* __restrict__ rsum,
    float* __restrict__ u_g, float* __restrict__ v_g,
    float* __restrict__ err_buf, float* __restrict__ S_buf, float* __restrict__ kl_buf,
    unsigned* __restrict__ bar_cnt, unsigned* __restrict__ bar_gen,
    float* __restrict__ out) {
    extern __shared__ float KrowF[];  // RPB_F * D floats = 64 KB
    int tid = threadIdx.x;
    int blk = blockIdx.x;
    int r = tid >> 5;
    int lane = tid & 31;
    int row = blk * RPB_F + r;
    unsigned lg = 0;

    {
        const float4* src = (const float4*)(Kg + (size_t)blk * RPB_F * D);
        float4* dst = (float4*)KrowF;
        for (int i = tid; i < RPB_F * D / 4; i += 256) dst[i] = src[i];
    }
    {
        const float4* p4 = (const float4*)(Pc + (size_t)row * D);
        float s = 0.0f;
        for (int k = lane; k < D / 4; k += 32) {
            float4 v = p4[k];
            s += (v.x + v.y) + (v.z + v.w);
        }
#pragma unroll
        for (int off = 16; off; off >>= 1) s += __shfl_xor(s, off, 32);
        if (lane == 0) rsum[row] = s;
    }
    __syncthreads();

    const float bval = 1.0f / (float)D;
    const float aval = 1.0f / (float)D;
    const float4* Kr4 = (const float4*)(KrowF + r * D);
    const float4* v4 = (const float4*)v_g;
    const float4* u4 = (const float4*)u_g;

    float p = 0.0f;
    for (int k = lane; k < D / 4; k += 32) {
        float4 a = Kr4[k];
        p += (a.x + a.y) + (a.z + a.w);
    }
#pragma unroll
    for (int off = 16; off; off >>= 1) p += __shfl_xor(p, off, 32);
    float Ku = p;

    float err = 1.0f;
    int cpt = 0;
    float v_r = 0.0f, u_r = 0.0f;
    while (err > STOPTHR && cpt < 500) {
        v_r = bval / (Ku + EPSV);
        if (lane == 0) v_g[row] = v_r;
        gbarN(bar_cnt, bar_gen, lg, NBLK_F);
        p = 0.0f;
        for (int k = lane; k < D / 4; k += 32) {
            float4 a = Kr4[k];
            float4 b = v4[k];
            p = fmaf(a.x, b.x, p); p = fmaf(a.y, b.y, p);
            p = fmaf(a.z, b.z, p); p = fmaf(a.w, b.w, p);
        }
#pragma unroll
        for (int off = 16; off; off >>= 1) p += __shfl_xor(p, off, 32);
        u_r = aval / (p + EPSV);
        if (lane == 0) u_g[row] = u_r;
        gbarN(bar_cnt, bar_gen, lg, NBLK_F);
        p = 0.0f;
        for (int k = lane; k < D / 4; k += 32) {
            float4 a = Kr4[k];
            float4 b = u4[k];
            p = fmaf(a.x, b.x, p); p = fmaf(a.y, b.y, p);
            p = fmaf(a.z, b.z, p); p = fmaf(a.w, b.w, p);
        }
#pragma unroll
        for (int off = 16; off; off >>= 1) p += __shfl_xor(p, off, 32);
        Ku = p;
        cpt++;
        if (cpt % 50 == 1) {
            int chk = cpt / 50;
            float e = fabsf(v_r * Ku - bval);
            e += __shfl_xor(e, 32, 64);
            if ((tid & 63) == 0) atomicAdd(&err_buf[chk], e);
            gbarN(bar_cnt, bar_gen, lg, NBLK_F);
            err = err_buf[chk];
        }
    }

    float pS = 0.0f;
    for (int k = lane; k < D / 4; k += 32) {
        float4 a = Kr4[k];
        float4 b = v4[k];
        pS += fmaxf(u_r * a.x * b.x, 1e-6f) + fmaxf(u_r * a.y * b.y, 1e-6f) +
              fmaxf(u_r * a.z * b.z, 1e-6f) + fmaxf(u_r * a.w * b.w, 1e-6f);
    }
#pragma unroll
    for (int off = 16; off; off >>= 1) pS += __shfl_xor(pS, off, 32);
    pS += __shfl_xor(pS, 32, 64);
    if ((tid & 63) == 0) atomicAdd(S_buf, pS);
    gbarN(bar_cnt, bar_gen, lg, NBLK_F);
    float logS = __logf(S_buf[0]);

    float invr_i = 1.0f / rsum[row];
    float pkl = 0.0f;
    const float4* Pc4 = (const float4*)(Pc + (size_t)row * D);
    const float4* rs4 = (const float4*)rsum;
    for (int k = lane; k < D / 4; k += 32) {
        float4 a = Kr4[k];
        float4 b = v4[k];
        float4 pc = Pc4[k];
        float4 rs = rs4[k];
        float P0 = pc.x * 0.5f * (invr_i + 1.0f / rs.x);
        float P1 = pc.y * 0.5f * (invr_i + 1.0f / rs.y);
        float P2 = pc.z * 0.5f * (invr_i + 1.0f / rs.z);
        float P3 = pc.w * 0.5f * (invr_i + 1.0f / rs.w);
        float q0 = fmaxf(u_r * a.x * b.x, 1e-6f);
        float q1 = fmaxf(u_r * a.y * b.y, 1e-6f);
        float q2 = fmaxf(u_r * a.z * b.z, 1e-6f);
        float q3 = fmaxf(u_r * a.w * b.w, 1e-6f);
        pkl += P0 * (__logf(P0) - __logf(q0) + logS);
        pkl += P1 * (__logf(P1) - __logf(q1) + logS);
        pkl += P2 * (__logf(P2) - __logf(q2) + logS);
        pkl += P3 * (__logf(P3) - __logf(q3) + logS);
    }
#pragma unroll
    for (int off = 16; off; off >>= 1) pkl += __shfl_xor(pkl, off, 32);
    pkl += __shfl_xor(pkl, 32, 64);
    if ((tid & 63) == 0) atomicAdd(kl_buf, pkl);
    gbarN(bar_cnt, bar_gen, lg, NBLK_F);
    if (blk == 0 && tid == 0) out[0] = kl_buf[0];
}

extern "C" void kernel_launch(void* const* d_in, const int* in_sizes, int n_in,
                              void* d_out, int out_size, void* d_ws, size_t ws_size,
                              hipStream_t stream) {
    const float* theta = (const float*)d_in[0];
    const float* emb = (const float*)d_in[1];
    float* out = (float*)d_out;

    char* ws = (char*)d_ws;
    float* Kg = (float*)ws;                      // 16 MiB
    float* Pc = (float*)(ws + (1u << 24));       // 16 MiB
    char* tail = ws + (1u << 25);
    float* sq   = (float*)(tail);
    float* nrm  = (float*)(tail + 8192);
    float* rsum = (float*)(tail + 16384);
    float* u_g  = (float*)(tail + 24576);
    float* v_g  = (float*)(tail + 32768);
    float* err_buf = (float*)(tail + 40960);     // 10 floats
    float* S_buf   = (float*)(tail + 41216);
    float* kl_buf  = (float*)(tail + 41472);
    unsigned* bar_cnt  = (unsigned*)(tail + 41728);
    unsigned* bar_gen  = (unsigned*)(tail + 41984);
    unsigned* bar_root = (unsigned*)(tail + 42240);
    unsigned* bar_leaf = (unsigned*)(tail + 49152);  // 8 slots * 128 B
    float* vslab = (float*)(tail + 65536);       // dense 2048 f32 = 8 KiB
    float* uslab = (float*)(tail + 65536 + 8192);
    unsigned short* Yth = (unsigned short*)(tail + 131072);               // 1 MiB used
    unsigned short* Yem = (unsigned short*)(tail + 131072 + (1u << 21));  // 1 MiB used

    // one-time opt-in for 128 KB dynamic LDS on the loop kernel; fall back if refused
    static int attr_ok = -1;
    if (attr_ok < 0) {
        attr_ok = (hipFuncSetAttribute((const void*)sinkhorn_loop_kernel,
                                       hipFuncAttributeMaxDynamicSharedMemorySize,
                                       RPB_L * D * sizeof(unsigned short)) == hipSuccess) ? 1 : 0;
    }

    rowstats_kernel<<<D, 256, 0, stream>>>(theta, emb, sq, nrm, Yth, Yem,
                                           err_buf, S_buf, kl_buf, bar_cnt, bar_gen,
                                           bar_leaf, bar_root);
    gram_mfma_kernel<<<dim3(16, 16, 2), 256, 0, stream>>>(Yth, Yem, sq, nrm, Kg, Pc);

    if (attr_ok == 1) {
        sinkhorn_loop_kernel<<<NBLK_L, 1024, RPB_L * D * sizeof(unsigned short), stream>>>(
            Kg, Pc, rsum, uslab, vslab, err_buf, S_buf, bar_leaf, bar_root, bar_gen);
        kl_kernel<<<NBLK_F, 256, 0, stream>>>(Kg, Pc, rsum, uslab, vslab, S_buf, out);
    } else {
        sinkhorn_kernel<<<NBLK_F, 256, RPB_F * D * sizeof(float), stream>>>(
            Kg, Pc, rsum, u_g, v_g, err_buf, S_buf, kl_buf, bar_cnt, bar_gen, out);
    }
}

// Round 10
// 127.648 us; speedup vs baseline: 1.0434x; 1.0434x over previous
//
#include <hip/hip_runtime.h>
#include <math.h>

#define D 2048
#define F 256
#define ALPHA 0.005f
#define STOPTHR 0.005f
#define EPSV 1e-16f

// fast path: 64 blocks x 1024 threads, 32 rows/block, bf16 K in 128KB dynamic LDS
#define NBLK_L 64
#define RPB_L 32
// fallback path (r2-proven): 256 blocks x 256 threads, 8 rows/block, f32 K
#define NBLK_F 256
#define RPB_F 8

typedef __bf16 bf16x8 __attribute__((ext_vector_type(8)));
typedef float f32x4 __attribute__((ext_vector_type(4)));
typedef unsigned short u16x8 __attribute__((ext_vector_type(8)));

__device__ __forceinline__ unsigned short f2bf(float f) {
    unsigned u = __float_as_uint(f);
    unsigned r = (u + 0x7FFFu + ((u >> 16) & 1u)) >> 16;  // RNE
    return (unsigned short)r;
}
__device__ __forceinline__ float bf2f(unsigned short b) {
    return __uint_as_float(((unsigned)b) << 16);
}
__device__ __forceinline__ float bflo(unsigned w) { return __uint_as_float(w << 16); }
__device__ __forceinline__ float bfhi(unsigned w) { return __uint_as_float(w & 0xFFFF0000u); }

// ---- flat central grid barrier (r0-r8 proven; r5 distributed / r9 tree both regressed) ----
__device__ __forceinline__ void gbarN(unsigned* cnt, unsigned* gen, unsigned& lg, int N) {
    __syncthreads();
    if (threadIdx.x == 0) {
        unsigned g = lg;
        unsigned a = __hip_atomic_fetch_add(cnt, 1u, __ATOMIC_ACQ_REL, __HIP_MEMORY_SCOPE_AGENT);
        if (a == (unsigned)(N - 1)) {
            __hip_atomic_store(cnt, 0u, __ATOMIC_RELAXED, __HIP_MEMORY_SCOPE_AGENT);
            __hip_atomic_store(gen, g + 1u, __ATOMIC_RELEASE, __HIP_MEMORY_SCOPE_AGENT);
        } else {
            while ((int)(__hip_atomic_load(gen, __ATOMIC_ACQUIRE, __HIP_MEMORY_SCOPE_AGENT) - (g + 1u)) < 0) {}
        }
    }
    __syncthreads();
    lg++;
}

// ---------------- row stats + plain-bf16 cast + flag/accum init ----------------
__global__ void rowstats_kernel(const float* __restrict__ theta,
                                const float* __restrict__ emb,
                                float* __restrict__ sq, float* __restrict__ nrm,
                                unsigned short* __restrict__ Yth,
                                unsigned short* __restrict__ Yem,
                                float* __restrict__ err_buf, float* __restrict__ S_buf,
                                float* __restrict__ kl_buf,
                                unsigned* __restrict__ bar_cnt, unsigned* __restrict__ bar_gen) {
    if (blockIdx.x == 0) {
        int t0 = threadIdx.x;
        if (t0 < 10) err_buf[t0] = 0.0f;
        else if (t0 == 10) S_buf[0] = 0.0f;
        else if (t0 == 11) kl_buf[0] = 0.0f;
        else if (t0 == 12) *bar_cnt = 0u;
        else if (t0 == 13) *bar_gen = 0u;
    }
    int row = blockIdx.x;
    int t = threadIdx.x;  // 256 threads == F
    float tv = theta[row * F + t];
    float ev = emb[row * F + t];

    Yth[row * F + t] = f2bf(tv);
    Yem[row * F + t] = f2bf(ev);

    float s1 = tv * tv, s2 = ev * ev;
    for (int off = 32; off; off >>= 1) {
        s1 += __shfl_down(s1, off, 64);
        s2 += __shfl_down(s2, off, 64);
    }
    __shared__ float w1[4], w2[4];
    int wid = t >> 6;
    if ((t & 63) == 0) { w1[wid] = s1; w2[wid] = s2; }
    __syncthreads();
    if (t == 0) {
        sq[row]  = w1[0] + w1[1] + w1[2] + w1[3];
        nrm[row] = sqrtf(w2[0] + w2[1] + w2[2] + w2[3]);
    }
}

// ---------------- Gram via bf16 MFMA, K=256 plain bf16 (r8-proven, frozen) ----------------
#define GBK 64
#define GPAD 72

__global__ __launch_bounds__(256) void gram_mfma_kernel(
    const unsigned short* __restrict__ Yth, const unsigned short* __restrict__ Yem,
    const float* __restrict__ sq, const float* __restrict__ nrm,
    float* __restrict__ Kg, float* __restrict__ Pc) {
    int z = blockIdx.z;
    const unsigned short* Y = z ? Yem : Yth;
    int brow = blockIdx.y * 128;
    int bcol = blockIdx.x * 128;
    __shared__ __align__(16) unsigned short PA[128 * GPAD];
    __shared__ __align__(16) unsigned short PB[128 * GPAD];
    int tid = threadIdx.x;
    int wid = tid >> 6, lane = tid & 63;
    int wr = wid >> 1, wc = wid & 1;
    int lr = lane & 15;
    int lk = (lane >> 4) * 8;

    f32x4 acc[4][4] = {};

    for (int k0 = 0; k0 < F; k0 += GBK) {
        __syncthreads();
#pragma unroll
        for (int q = 0; q < 4; q++) {
            int c = tid + q * 256;
            int rw = c >> 3, ch = (c & 7) * 8;
            *(float4*)&PA[rw * GPAD + ch] =
                *(const float4*)&Y[(size_t)(brow + rw) * F + k0 + ch];
            *(float4*)&PB[rw * GPAD + ch] =
                *(const float4*)&Y[(size_t)(bcol + rw) * F + k0 + ch];
        }
        __syncthreads();
#pragma unroll
        for (int ks = 0; ks < 2; ks++) {
            bf16x8 af[4], bff[4];
#pragma unroll
            for (int m = 0; m < 4; m++)
                af[m] = *(const bf16x8*)&PA[(wr * 64 + m * 16 + lr) * GPAD + ks * 32 + lk];
#pragma unroll
            for (int n = 0; n < 4; n++)
                bff[n] = *(const bf16x8*)&PB[(wc * 64 + n * 16 + lr) * GPAD + ks * 32 + lk];
#pragma unroll
            for (int m = 0; m < 4; m++)
#pragma unroll
                for (int n = 0; n < 4; n++)
                    acc[m][n] = __builtin_amdgcn_mfma_f32_16x16x32_bf16(
                        af[m], bff[n], acc[m][n], 0, 0, 0);
        }
    }

    int ib = brow + wr * 64;
    int jb = bcol + wc * 64;
    int rr = (lane >> 4) * 4;
    if (z == 0) {
        float sqi[4][4];
#pragma unroll
        for (int m = 0; m < 4; m++)
#pragma unroll
            for (int q = 0; q < 4; q++) sqi[m][q] = sq[ib + m * 16 + rr + q];
#pragma unroll
        for (int n = 0; n < 4; n++) {
            int j = jb + n * 16 + lr;
            float sqj = sq[j];
#pragma unroll
            for (int m = 0; m < 4; m++)
#pragma unroll
                for (int q = 0; q < 4; q++) {
                    int i = ib + m * 16 + rr + q;
                    float cc = fmaxf(sqi[m][q] + sqj - 2.0f * acc[m][n][q], 0.0f);
                    Kg[(size_t)i * D + j] = __expf(-ALPHA * cc);
                }
        }
    } else {
        float nri[4][4];
#pragma unroll
        for (int m = 0; m < 4; m++)
#pragma unroll
            for (int q = 0; q < 4; q++) nri[m][q] = nrm[ib + m * 16 + rr + q];
#pragma unroll
        for (int n = 0; n < 4; n++) {
            int j = jb + n * 16 + lr;
            float nrj = nrm[j];
#pragma unroll
            for (int m = 0; m < 4; m++)
#pragma unroll
                for (int q = 0; q < 4; q++) {
                    int i = ib + m * 16 + rr + q;
                    Pc[(size_t)i * D + j] = acc[m][n][q] / (nri[m][q] * nrj + EPSV);
                }
        }
    }
}

// ========== FAST PATH: 64 blocks x 1024 threads, 32 rows/block, bf16 K, flat gbar ==========
// KL epilogue merged into the tail (kl_kernel launch removed): K from LDS bf16
// (log-arg rel err ~0.4% -> KL abs err ~0.004, threshold 312), v from vbuf, u_r local.
__global__ __launch_bounds__(1024) void sinkhorn_loop_kernel(
    const float* __restrict__ Kg, const float* __restrict__ Pc,
    float* __restrict__ rsum,
    float* __restrict__ uslab, float* __restrict__ vslab,
    float* __restrict__ err_buf, float* __restrict__ S_buf,
    unsigned* __restrict__ bar_cnt, unsigned* __restrict__ bar_gen,
    float* __restrict__ out) {
    extern __shared__ unsigned short Krow_bf[];  // RPB_L * D bf16 = 128 KB dynamic
    __shared__ float vbuf[D], ubuf[D];           // 16 KB static
    __shared__ float redw[16];                   // per-wave scratch for block reduce
    int tid = threadIdx.x;
    int blk = blockIdx.x;
    int r = tid >> 5;        // 0..31
    int lane = tid & 31;
    int row = blk * RPB_L + r;
    unsigned lg = 0;

    // stage 32 K-rows f32 -> bf16 LDS
    {
        const float4* src = (const float4*)(Kg + (size_t)blk * RPB_L * D);
        for (int i = tid; i < RPB_L * D / 8; i += 1024) {
            float4 a = src[i * 2], b = src[i * 2 + 1];
            u16x8 w;
            w[0] = f2bf(a.x); w[1] = f2bf(a.y); w[2] = f2bf(a.z); w[3] = f2bf(a.w);
            w[4] = f2bf(b.x); w[5] = f2bf(b.y); w[6] = f2bf(b.z); w[7] = f2bf(b.w);
            *(u16x8*)&Krow_bf[i * 8] = w;
        }
    }
    // rsum of Pc for this block's 32 rows (KL reads it after the S barrier)
    {
        const float4* p4 = (const float4*)(Pc + (size_t)row * D);
        float s = 0.0f;
        for (int k = lane; k < D / 4; k += 32) {
            float4 v = p4[k];
            s += (v.x + v.y) + (v.z + v.w);
        }
#pragma unroll
        for (int off = 16; off; off >>= 1) s += __shfl_xor(s, off, 32);
        if (lane == 0) rsum[row] = s;
    }
    __syncthreads();

    const float bval = 1.0f / (float)D;
    const float aval = 1.0f / (float)D;
    const unsigned short* Kr = &Krow_bf[r * D];

    // Ku for u0 = ones: row sum (from bf16)
    float p = 0.0f;
    for (int k8 = lane; k8 < D / 8; k8 += 32) {
        uint4 kw = *(const uint4*)&Kr[k8 * 8];
        p += bflo(kw.x) + bfhi(kw.x) + bflo(kw.y) + bfhi(kw.y) +
             bflo(kw.z) + bfhi(kw.z) + bflo(kw.w) + bfhi(kw.w);
    }
#pragma unroll
    for (int off = 16; off; off >>= 1) p += __shfl_xor(p, off, 32);
    float Ku = p;

    const float4* vsl4 = (const float4*)vslab;
    const float4* usl4 = (const float4*)uslab;
    float4* vb4w = (float4*)vbuf;
    float4* ub4w = (float4*)ubuf;
    const float4* vb4 = (const float4*)vbuf;
    const float4* ub4 = (const float4*)ubuf;

    float err = 1.0f;
    int cpt = 0;
    float v_r = 0.0f, u_r = 0.0f;
    while (err > STOPTHR && cpt < 500) {
        v_r = bval / (Ku + EPSV);
        if (lane == 0) vslab[row] = v_r;
        gbarN(bar_cnt, bar_gen, lg, NBLK_L);
        if (tid < D / 4) vb4w[tid] = vsl4[tid];  // bounce v -> dense LDS
        __syncthreads();
        p = 0.0f;
        for (int k8 = lane; k8 < D / 8; k8 += 32) {
            uint4 kw = *(const uint4*)&Kr[k8 * 8];
            float4 v0 = vb4[k8 * 2], v1 = vb4[k8 * 2 + 1];
            p = fmaf(bflo(kw.x), v0.x, p); p = fmaf(bfhi(kw.x), v0.y, p);
            p = fmaf(bflo(kw.y), v0.z, p); p = fmaf(bfhi(kw.y), v0.w, p);
            p = fmaf(bflo(kw.z), v1.x, p); p = fmaf(bfhi(kw.z), v1.y, p);
            p = fmaf(bflo(kw.w), v1.z, p); p = fmaf(bfhi(kw.w), v1.w, p);
        }
#pragma unroll
        for (int off = 16; off; off >>= 1) p += __shfl_xor(p, off, 32);
        u_r = aval / (p + EPSV);
        if (lane == 0) uslab[row] = u_r;
        gbarN(bar_cnt, bar_gen, lg, NBLK_L);
        if (tid < D / 4) ub4w[tid] = usl4[tid];  // bounce u -> dense LDS
        __syncthreads();
        p = 0.0f;
        for (int k8 = lane; k8 < D / 8; k8 += 32) {
            uint4 kw = *(const uint4*)&Kr[k8 * 8];
            float4 u0 = ub4[k8 * 2], u1 = ub4[k8 * 2 + 1];
            p = fmaf(bflo(kw.x), u0.x, p); p = fmaf(bfhi(kw.x), u0.y, p);
            p = fmaf(bflo(kw.y), u0.z, p); p = fmaf(bfhi(kw.y), u0.w, p);
            p = fmaf(bflo(kw.z), u1.x, p); p = fmaf(bfhi(kw.z), u1.y, p);
            p = fmaf(bflo(kw.w), u1.z, p); p = fmaf(bfhi(kw.w), u1.w, p);
        }
#pragma unroll
        for (int off = 16; off; off >>= 1) p += __shfl_xor(p, off, 32);
        Ku = p;
        cpt++;
        if (cpt % 50 == 1) {
            int chk = cpt / 50;  // 0..9
            float e = fabsf(v_r * Ku - bval);   // uniform across the row's 32 lanes
            e += __shfl_xor(e, 32, 64);         // pair the wave's two rows
            if ((tid & 63) == 0) redw[tid >> 6] = e;
            __syncthreads();
            if (tid == 0) {                      // ONE atomic per block
                float s = 0.0f;
#pragma unroll
                for (int i = 0; i < 16; i++) s += redw[i];
                atomicAdd(&err_buf[chk], s);
            }
            gbarN(bar_cnt, bar_gen, lg, NBLK_L);
            err = err_buf[chk];
        }
    }

    // ---- S = sum(max(u_i K_ij v_j, 1e-6)) ----
    float pS = 0.0f;
    for (int k8 = lane; k8 < D / 8; k8 += 32) {
        uint4 kw = *(const uint4*)&Kr[k8 * 8];
        float4 v0 = vb4[k8 * 2], v1 = vb4[k8 * 2 + 1];
        pS += fmaxf(u_r * bflo(kw.x) * v0.x, 1e-6f) + fmaxf(u_r * bfhi(kw.x) * v0.y, 1e-6f) +
              fmaxf(u_r * bflo(kw.y) * v0.z, 1e-6f) + fmaxf(u_r * bfhi(kw.y) * v0.w, 1e-6f) +
              fmaxf(u_r * bflo(kw.z) * v1.x, 1e-6f) + fmaxf(u_r * bfhi(kw.z) * v1.y, 1e-6f) +
              fmaxf(u_r * bflo(kw.w) * v1.z, 1e-6f) + fmaxf(u_r * bfhi(kw.w) * v1.w, 1e-6f);
    }
#pragma unroll
    for (int off = 16; off; off >>= 1) pS += __shfl_xor(pS, off, 32);
    pS += __shfl_xor(pS, 32, 64);
    if ((tid & 63) == 0) redw[tid >> 6] = pS;
    __syncthreads();
    if (tid == 0) {
        float s = 0.0f;
#pragma unroll
        for (int i = 0; i < 16; i++) s += redw[i];
        atomicAdd(S_buf, s);
    }
    gbarN(bar_cnt, bar_gen, lg, NBLK_L);  // S complete grid-wide

    // ---- KL epilogue (was kl_kernel): K from LDS bf16, v from vbuf, u_r local ----
    float logS = __logf(S_buf[0]);
    float invr_i = 1.0f / rsum[row];
    float pkl = 0.0f;
    const float4* pc4  = (const float4*)(Pc + (size_t)row * D);
    const float4* rs4g = (const float4*)rsum;
    for (int k = lane; k < D / 4; k += 32) {
        uint2 kw = *(const uint2*)&Kr[k * 4];
        float K0 = bflo(kw.x), K1 = bfhi(kw.x), K2 = bflo(kw.y), K3 = bfhi(kw.y);
        float4 pc = pc4[k];
        float4 rs = rs4g[k];
        float4 b = vb4[k];
        float P0 = pc.x * 0.5f * (invr_i + 1.0f / rs.x);
        float P1 = pc.y * 0.5f * (invr_i + 1.0f / rs.y);
        float P2 = pc.z * 0.5f * (invr_i + 1.0f / rs.z);
        float P3 = pc.w * 0.5f * (invr_i + 1.0f / rs.w);
        float q0 = fmaxf(u_r * K0 * b.x, 1e-6f);
        float q1 = fmaxf(u_r * K1 * b.y, 1e-6f);
        float q2 = fmaxf(u_r * K2 * b.z, 1e-6f);
        float q3 = fmaxf(u_r * K3 * b.w, 1e-6f);
        pkl += P0 * (__logf(P0) - __logf(q0) + logS);
        pkl += P1 * (__logf(P1) - __logf(q1) + logS);
        pkl += P2 * (__logf(P2) - __logf(q2) + logS);
        pkl += P3 * (__logf(P3) - __logf(q3) + logS);
    }
#pragma unroll
    for (int off = 16; off; off >>= 1) pkl += __shfl_xor(pkl, off, 32);
    pkl += __shfl_xor(pkl, 32, 64);
    if ((tid & 63) == 0) redw[tid >> 6] = pkl;
    __syncthreads();
    if (tid == 0) {
        float s = 0.0f;
#pragma unroll
        for (int i = 0; i < 16; i++) s += redw[i];
        atomicAdd(out, s);  // out memset to 0 by harness per replay
    }
}

// ========== FALLBACK: r2-proven monolithic sinkhorn (256 blocks, flat gbar) ==========
__global__ __launch_bounds__(256) void sinkhorn_kernel(
    const float* __restrict__ Kg, const float* __restrict__ Pc,
    float* __restrict__ rsum,
    float* __restrict__ u_g, float* __restrict__ v_g,
    float* __restrict__ err_buf, float* __restrict__ S_buf, float* __restrict__ kl_buf,
    unsigned* __restrict__ bar_cnt, unsigned* __restrict__ bar_gen,
    float* __restrict__ out) {
    extern __shared__ float KrowF[];  // RPB_F * D floats = 64 KB
    int tid = threadIdx.x;
    int blk = blockIdx.x;
    int r = tid >> 5;
    int lane = tid & 31;
    int row = blk * RPB_F + r;
    unsigned lg = 0;

    {
        const float4* src = (const float4*)(Kg + (size_t)blk * RPB_F * D);
        float4* dst = (float4*)KrowF;
        for (int i = tid; i < RPB_F * D / 4; i += 256) dst[i] = src[i];
    }
    {
        const float4* p4 = (const float4*)(Pc + (size_t)row * D);
        float s = 0.0f;
        for (int k = lane; k < D / 4; k += 32) {
            float4 v = p4[k];
            s += (v.x + v.y) + (v.z + v.w);
        }
#pragma unroll
        for (int off = 16; off; off >>= 1) s += __shfl_xor(s, off, 32);
        if (lane == 0) rsum[row] = s;
    }
    __syncthreads();

    const float bval = 1.0f / (float)D;
    const float aval = 1.0f / (float)D;
    const float4* Kr4 = (const float4*)(KrowF + r * D);
    const float4* v4 = (const float4*)v_g;
    const float4* u4 = (const float4*)u_g;

    float p = 0.0f;
    for (int k = lane; k < D / 4; k += 32) {
        float4 a = Kr4[k];
        p += (a.x + a.y) + (a.z + a.w);
    }
#pragma unroll
    for (int off = 16; off; off >>= 1) p += __shfl_xor(p, off, 32);
    float Ku = p;

    float err = 1.0f;
    int cpt = 0;
    float v_r = 0.0f, u_r = 0.0f;
    while (err > STOPTHR && cpt < 500) {
        v_r = bval / (Ku + EPSV);
        if (lane == 0) v_g[row] = v_r;
        gbarN(bar_cnt, bar_gen, lg, NBLK_F);
        p = 0.0f;
        for (int k = lane; k < D / 4; k += 32) {
            float4 a = Kr4[k];
            float4 b = v4[k];
            p = fmaf(a.x, b.x, p); p = fmaf(a.y, b.y, p);
            p = fmaf(a.z, b.z, p); p = fmaf(a.w, b.w, p);
        }
#pragma unroll
        for (int off = 16; off; off >>= 1) p += __shfl_xor(p, off, 32);
        u_r = aval / (p + EPSV);
        if (lane == 0) u_g[row] = u_r;
        gbarN(bar_cnt, bar_gen, lg, NBLK_F);
        p = 0.0f;
        for (int k = lane; k < D / 4; k += 32) {
            float4 a = Kr4[k];
            float4 b = u4[k];
            p = fmaf(a.x, b.x, p); p = fmaf(a.y, b.y, p);
            p = fmaf(a.z, b.z, p); p = fmaf(a.w, b.w, p);
        }
#pragma unroll
        for (int off = 16; off; off >>= 1) p += __shfl_xor(p, off, 32);
        Ku = p;
        cpt++;
        if (cpt % 50 == 1) {
            int chk = cpt / 50;
            float e = fabsf(v_r * Ku - bval);
            e += __shfl_xor(e, 32, 64);
            if ((tid & 63) == 0) atomicAdd(&err_buf[chk], e);
            gbarN(bar_cnt, bar_gen, lg, NBLK_F);
            err = err_buf[chk];
        }
    }

    float pS = 0.0f;
    for (int k = lane; k < D / 4; k += 32) {
        float4 a = Kr4[k];
        float4 b = v4[k];
        pS += fmaxf(u_r * a.x * b.x, 1e-6f) + fmaxf(u_r * a.y * b.y, 1e-6f) +
              fmaxf(u_r * a.z * b.z, 1e-6f) + fmaxf(u_r * a.w * b.w, 1e-6f);
    }
#pragma unroll
    for (int off = 16; off; off >>= 1) pS += __shfl_xor(pS, off, 32);
    pS += __shfl_xor(pS, 32, 64);
    if ((tid & 63) == 0) atomicAdd(S_buf, pS);
    gbarN(bar_cnt, bar_gen, lg, NBLK_F);
    float logS = __logf(S_buf[0]);

    float invr_i = 1.0f / rsum[row];
    float pkl = 0.0f;
    const float4* Pc4 = (const float4*)(Pc + (size_t)row * D);
    const float4* rs4 = (const float4*)rsum;
    for (int k = lane; k < D / 4; k += 32) {
        float4 a = Kr4[k];
        float4 b = v4[k];
        float4 pc = Pc4[k];
        float4 rs = rs4[k];
        float P0 = pc.x * 0.5f * (invr_i + 1.0f / rs.x);
        float P1 = pc.y * 0.5f * (invr_i + 1.0f / rs.y);
        float P2 = pc.z * 0.5f * (invr_i + 1.0f / rs.z);
        float P3 = pc.w * 0.5f * (invr_i + 1.0f / rs.w);
        float q0 = fmaxf(u_r * a.x * b.x, 1e-6f);
        float q1 = fmaxf(u_r * a.y * b.y, 1e-6f);
        float q2 = fmaxf(u_r * a.z * b.z, 1e-6f);
        float q3 = fmaxf(u_r * a.w * b.w, 1e-6f);
        pkl += P0 * (__logf(P0) - __logf(q0) + logS);
        pkl += P1 * (__logf(P1) - __logf(q1) + logS);
        pkl += P2 * (__logf(P2) - __logf(q2) + logS);
        pkl += P3 * (__logf(P3) - __logf(q3) + logS);
    }
#pragma unroll
    for (int off = 16; off; off >>= 1) pkl += __shfl_xor(pkl, off, 32);
    pkl += __shfl_xor(pkl, 32, 64);
    if ((tid & 63) == 0) atomicAdd(kl_buf, pkl);
    gbarN(bar_cnt, bar_gen, lg, NBLK_F);
    if (blk == 0 && tid == 0) out[0] = kl_buf[0];
}

extern "C" void kernel_launch(void* const* d_in, const int* in_sizes, int n_in,
                              void* d_out, int out_size, void* d_ws, size_t ws_size,
                              hipStream_t stream) {
    const float* theta = (const float*)d_in[0];
    const float* emb = (const float*)d_in[1];
    float* out = (float*)d_out;

    char* ws = (char*)d_ws;
    float* Kg = (float*)ws;                      // 16 MiB
    float* Pc = (float*)(ws + (1u << 24));       // 16 MiB
    char* tail = ws + (1u << 25);
    float* sq   = (float*)(tail);
    float* nrm  = (float*)(tail + 8192);
    float* rsum = (float*)(tail + 16384);
    float* u_g  = (float*)(tail + 24576);
    float* v_g  = (float*)(tail + 32768);
    float* err_buf = (float*)(tail + 40960);     // 10 floats
    float* S_buf   = (float*)(tail + 41216);
    float* kl_buf  = (float*)(tail + 41472);
    unsigned* bar_cnt  = (unsigned*)(tail + 41728);
    unsigned* bar_gen  = (unsigned*)(tail + 41984);
    float* vslab = (float*)(tail + 65536);       // dense 2048 f32 = 8 KiB
    float* uslab = (float*)(tail + 65536 + 8192);
    unsigned short* Yth = (unsigned short*)(tail + 131072);               // 1 MiB used
    unsigned short* Yem = (unsigned short*)(tail + 131072 + (1u << 21));  // 1 MiB used

    // one-time opt-in for 128 KB dynamic LDS on the loop kernel; fall back if refused
    static int attr_ok = -1;
    if (attr_ok < 0) {
        attr_ok = (hipFuncSetAttribute((const void*)sinkhorn_loop_kernel,
                                       hipFuncAttributeMaxDynamicSharedMemorySize,
                                       RPB_L * D * sizeof(unsigned short)) == hipSuccess) ? 1 : 0;
    }

    rowstats_kernel<<<D, 256, 0, stream>>>(theta, emb, sq, nrm, Yth, Yem,
                                           err_buf, S_buf, kl_buf, bar_cnt, bar_gen);
    gram_mfma_kernel<<<dim3(16, 16, 2), 256, 0, stream>>>(Yth, Yem, sq, nrm, Kg, Pc);

    if (attr_ok == 1) {
        sinkhorn_loop_kernel<<<NBLK_L, 1024, RPB_L * D * sizeof(unsigned short), stream>>>(
            Kg, Pc, rsum, uslab, vslab, err_buf, S_buf, bar_cnt, bar_gen, out);
    } else {
        sinkhorn_kernel<<<NBLK_F, 256, RPB_F * D * sizeof(float), stream>>>(
            Kg, Pc, rsum, u_g, v_g, err_buf, S_buf, kl_buf, bar_cnt, bar_gen, out);
    }
}

// Round 11
// 117.829 us; speedup vs baseline: 1.1303x; 1.0833x over previous
//
#include <hip/hip_runtime.h>
#include <math.h>

#define D 2048
#define F 256
#define ALPHA 0.005f
#define STOPTHR 0.005f
#define EPSV 1e-16f

// fast path: 64 blocks x 1024 threads, 32 rows/block, bf16 K in 128KB dynamic LDS
#define NBLK_L 64
#define RPB_L 32
// fallback path (r2-proven): 256 blocks x 256 threads, 8 rows/block, f32 K
#define NBLK_F 256
#define RPB_F 8

typedef __bf16 bf16x8 __attribute__((ext_vector_type(8)));
typedef float f32x4 __attribute__((ext_vector_type(4)));
typedef unsigned short u16x8 __attribute__((ext_vector_type(8)));

__device__ __forceinline__ unsigned short f2bf(float f) {
    unsigned u = __float_as_uint(f);
    unsigned r = (u + 0x7FFFu + ((u >> 16) & 1u)) >> 16;  // RNE
    return (unsigned short)r;
}
__device__ __forceinline__ float bf2f(unsigned short b) {
    return __uint_as_float(((unsigned)b) << 16);
}
__device__ __forceinline__ float bflo(unsigned w) { return __uint_as_float(w << 16); }
__device__ __forceinline__ float bfhi(unsigned w) { return __uint_as_float(w & 0xFFFF0000u); }

// ---- flat central grid barrier (r0-r8 proven; r5 distributed / r9 tree both regressed) ----
__device__ __forceinline__ void gbarN(unsigned* cnt, unsigned* gen, unsigned& lg, int N) {
    __syncthreads();
    if (threadIdx.x == 0) {
        unsigned g = lg;
        unsigned a = __hip_atomic_fetch_add(cnt, 1u, __ATOMIC_ACQ_REL, __HIP_MEMORY_SCOPE_AGENT);
        if (a == (unsigned)(N - 1)) {
            __hip_atomic_store(cnt, 0u, __ATOMIC_RELAXED, __HIP_MEMORY_SCOPE_AGENT);
            __hip_atomic_store(gen, g + 1u, __ATOMIC_RELEASE, __HIP_MEMORY_SCOPE_AGENT);
        } else {
            while ((int)(__hip_atomic_load(gen, __ATOMIC_ACQUIRE, __HIP_MEMORY_SCOPE_AGENT) - (g + 1u)) < 0) {}
        }
    }
    __syncthreads();
    lg++;
}

// ---------------- row stats + plain-bf16 cast + flag/accum init ----------------
__global__ void rowstats_kernel(const float* __restrict__ theta,
                                const float* __restrict__ emb,
                                float* __restrict__ sq, float* __restrict__ nrm,
                                unsigned short* __restrict__ Yth,
                                unsigned short* __restrict__ Yem,
                                float* __restrict__ err_buf, float* __restrict__ S_buf,
                                float* __restrict__ kl_buf,
                                unsigned* __restrict__ bar_cnt, unsigned* __restrict__ bar_gen) {
    if (blockIdx.x == 0) {
        int t0 = threadIdx.x;
        if (t0 < 10) err_buf[t0] = 0.0f;
        else if (t0 == 10) S_buf[0] = 0.0f;
        else if (t0 == 11) kl_buf[0] = 0.0f;
        else if (t0 == 12) *bar_cnt = 0u;
        else if (t0 == 13) *bar_gen = 0u;
    }
    int row = blockIdx.x;
    int t = threadIdx.x;  // 256 threads == F
    float tv = theta[row * F + t];
    float ev = emb[row * F + t];

    Yth[row * F + t] = f2bf(tv);
    Yem[row * F + t] = f2bf(ev);

    float s1 = tv * tv, s2 = ev * ev;
    for (int off = 32; off; off >>= 1) {
        s1 += __shfl_down(s1, off, 64);
        s2 += __shfl_down(s2, off, 64);
    }
    __shared__ float w1[4], w2[4];
    int wid = t >> 6;
    if ((t & 63) == 0) { w1[wid] = s1; w2[wid] = s2; }
    __syncthreads();
    if (t == 0) {
        sq[row]  = w1[0] + w1[1] + w1[2] + w1[3];
        nrm[row] = sqrtf(w2[0] + w2[1] + w2[2] + w2[3]);
    }
}

// ---------------- Gram via bf16 MFMA, K=256 plain bf16 (r8-proven, frozen) ----------------
#define GBK 64
#define GPAD 72

__global__ __launch_bounds__(256) void gram_mfma_kernel(
    const unsigned short* __restrict__ Yth, const unsigned short* __restrict__ Yem,
    const float* __restrict__ sq, const float* __restrict__ nrm,
    float* __restrict__ Kg, float* __restrict__ Pc) {
    int z = blockIdx.z;
    const unsigned short* Y = z ? Yem : Yth;
    int brow = blockIdx.y * 128;
    int bcol = blockIdx.x * 128;
    __shared__ __align__(16) unsigned short PA[128 * GPAD];
    __shared__ __align__(16) unsigned short PB[128 * GPAD];
    int tid = threadIdx.x;
    int wid = tid >> 6, lane = tid & 63;
    int wr = wid >> 1, wc = wid & 1;
    int lr = lane & 15;
    int lk = (lane >> 4) * 8;

    f32x4 acc[4][4] = {};

    for (int k0 = 0; k0 < F; k0 += GBK) {
        __syncthreads();
#pragma unroll
        for (int q = 0; q < 4; q++) {
            int c = tid + q * 256;
            int rw = c >> 3, ch = (c & 7) * 8;
            *(float4*)&PA[rw * GPAD + ch] =
                *(const float4*)&Y[(size_t)(brow + rw) * F + k0 + ch];
            *(float4*)&PB[rw * GPAD + ch] =
                *(const float4*)&Y[(size_t)(bcol + rw) * F + k0 + ch];
        }
        __syncthreads();
#pragma unroll
        for (int ks = 0; ks < 2; ks++) {
            bf16x8 af[4], bff[4];
#pragma unroll
            for (int m = 0; m < 4; m++)
                af[m] = *(const bf16x8*)&PA[(wr * 64 + m * 16 + lr) * GPAD + ks * 32 + lk];
#pragma unroll
            for (int n = 0; n < 4; n++)
                bff[n] = *(const bf16x8*)&PB[(wc * 64 + n * 16 + lr) * GPAD + ks * 32 + lk];
#pragma unroll
            for (int m = 0; m < 4; m++)
#pragma unroll
                for (int n = 0; n < 4; n++)
                    acc[m][n] = __builtin_amdgcn_mfma_f32_16x16x32_bf16(
                        af[m], bff[n], acc[m][n], 0, 0, 0);
        }
    }

    int ib = brow + wr * 64;
    int jb = bcol + wc * 64;
    int rr = (lane >> 4) * 4;
    if (z == 0) {
        float sqi[4][4];
#pragma unroll
        for (int m = 0; m < 4; m++)
#pragma unroll
            for (int q = 0; q < 4; q++) sqi[m][q] = sq[ib + m * 16 + rr + q];
#pragma unroll
        for (int n = 0; n < 4; n++) {
            int j = jb + n * 16 + lr;
            float sqj = sq[j];
#pragma unroll
            for (int m = 0; m < 4; m++)
#pragma unroll
                for (int q = 0; q < 4; q++) {
                    int i = ib + m * 16 + rr + q;
                    float cc = fmaxf(sqi[m][q] + sqj - 2.0f * acc[m][n][q], 0.0f);
                    Kg[(size_t)i * D + j] = __expf(-ALPHA * cc);
                }
        }
    } else {
        float nri[4][4];
#pragma unroll
        for (int m = 0; m < 4; m++)
#pragma unroll
            for (int q = 0; q < 4; q++) nri[m][q] = nrm[ib + m * 16 + rr + q];
#pragma unroll
        for (int n = 0; n < 4; n++) {
            int j = jb + n * 16 + lr;
            float nrj = nrm[j];
#pragma unroll
            for (int m = 0; m < 4; m++)
#pragma unroll
                for (int q = 0; q < 4; q++) {
                    int i = ib + m * 16 + rr + q;
                    Pc[(size_t)i * D + j] = acc[m][n][q] / (nri[m][q] * nrj + EPSV);
                }
        }
    }
}

// ========== FAST PATH: 64 blocks x 1024 threads, 32 rows/block, bf16 K, flat gbar ==========
// KL tail: clamp-vote skips logq (plan entries ~2.4e-7 << 1e-6 clamp), 1/rsum LDS table,
// logS folded out via per-lane P-sum.
__global__ __launch_bounds__(1024) void sinkhorn_loop_kernel(
    const float* __restrict__ Kg, const float* __restrict__ Pc,
    float* __restrict__ rsum,
    float* __restrict__ uslab, float* __restrict__ vslab,
    float* __restrict__ err_buf, float* __restrict__ S_buf,
    unsigned* __restrict__ bar_cnt, unsigned* __restrict__ bar_gen,
    float* __restrict__ out) {
    extern __shared__ unsigned short Krow_bf[];  // RPB_L * D bf16 = 128 KB dynamic
    __shared__ float vbuf[D], ubuf[D], rbuf[D];  // 24 KB static (rbuf = 1/rsum table)
    __shared__ float redw[16];                   // per-wave scratch for block reduce
    int tid = threadIdx.x;
    int blk = blockIdx.x;
    int r = tid >> 5;        // 0..31
    int lane = tid & 31;
    int row = blk * RPB_L + r;
    unsigned lg = 0;

    // stage 32 K-rows f32 -> bf16 LDS
    {
        const float4* src = (const float4*)(Kg + (size_t)blk * RPB_L * D);
        for (int i = tid; i < RPB_L * D / 8; i += 1024) {
            float4 a = src[i * 2], b = src[i * 2 + 1];
            u16x8 w;
            w[0] = f2bf(a.x); w[1] = f2bf(a.y); w[2] = f2bf(a.z); w[3] = f2bf(a.w);
            w[4] = f2bf(b.x); w[5] = f2bf(b.y); w[6] = f2bf(b.z); w[7] = f2bf(b.w);
            *(u16x8*)&Krow_bf[i * 8] = w;
        }
    }
    // rsum of Pc for this block's 32 rows (KL reads it after the S barrier)
    {
        const float4* p4 = (const float4*)(Pc + (size_t)row * D);
        float s = 0.0f;
        for (int k = lane; k < D / 4; k += 32) {
            float4 v = p4[k];
            s += (v.x + v.y) + (v.z + v.w);
        }
#pragma unroll
        for (int off = 16; off; off >>= 1) s += __shfl_xor(s, off, 32);
        if (lane == 0) rsum[row] = s;
    }
    __syncthreads();

    const float bval = 1.0f / (float)D;
    const float aval = 1.0f / (float)D;
    const unsigned short* Kr = &Krow_bf[r * D];

    // Ku for u0 = ones: row sum (from bf16)
    float p = 0.0f;
    for (int k8 = lane; k8 < D / 8; k8 += 32) {
        uint4 kw = *(const uint4*)&Kr[k8 * 8];
        p += bflo(kw.x) + bfhi(kw.x) + bflo(kw.y) + bfhi(kw.y) +
             bflo(kw.z) + bfhi(kw.z) + bflo(kw.w) + bfhi(kw.w);
    }
#pragma unroll
    for (int off = 16; off; off >>= 1) p += __shfl_xor(p, off, 32);
    float Ku = p;

    const float4* vsl4 = (const float4*)vslab;
    const float4* usl4 = (const float4*)uslab;
    float4* vb4w = (float4*)vbuf;
    float4* ub4w = (float4*)ubuf;
    const float4* vb4 = (const float4*)vbuf;
    const float4* ub4 = (const float4*)ubuf;

    float err = 1.0f;
    int cpt = 0;
    float v_r = 0.0f, u_r = 0.0f;
    while (err > STOPTHR && cpt < 500) {
        v_r = bval / (Ku + EPSV);
        if (lane == 0) vslab[row] = v_r;
        gbarN(bar_cnt, bar_gen, lg, NBLK_L);
        if (tid < D / 4) vb4w[tid] = vsl4[tid];  // bounce v -> dense LDS
        __syncthreads();
        p = 0.0f;
        for (int k8 = lane; k8 < D / 8; k8 += 32) {
            uint4 kw = *(const uint4*)&Kr[k8 * 8];
            float4 v0 = vb4[k8 * 2], v1 = vb4[k8 * 2 + 1];
            p = fmaf(bflo(kw.x), v0.x, p); p = fmaf(bfhi(kw.x), v0.y, p);
            p = fmaf(bflo(kw.y), v0.z, p); p = fmaf(bfhi(kw.y), v0.w, p);
            p = fmaf(bflo(kw.z), v1.x, p); p = fmaf(bfhi(kw.z), v1.y, p);
            p = fmaf(bflo(kw.w), v1.z, p); p = fmaf(bfhi(kw.w), v1.w, p);
        }
#pragma unroll
        for (int off = 16; off; off >>= 1) p += __shfl_xor(p, off, 32);
        u_r = aval / (p + EPSV);
        if (lane == 0) uslab[row] = u_r;
        gbarN(bar_cnt, bar_gen, lg, NBLK_L);
        if (tid < D / 4) ub4w[tid] = usl4[tid];  // bounce u -> dense LDS
        __syncthreads();
        p = 0.0f;
        for (int k8 = lane; k8 < D / 8; k8 += 32) {
            uint4 kw = *(const uint4*)&Kr[k8 * 8];
            float4 u0 = ub4[k8 * 2], u1 = ub4[k8 * 2 + 1];
            p = fmaf(bflo(kw.x), u0.x, p); p = fmaf(bfhi(kw.x), u0.y, p);
            p = fmaf(bflo(kw.y), u0.z, p); p = fmaf(bfhi(kw.y), u0.w, p);
            p = fmaf(bflo(kw.z), u1.x, p); p = fmaf(bfhi(kw.z), u1.y, p);
            p = fmaf(bflo(kw.w), u1.z, p); p = fmaf(bfhi(kw.w), u1.w, p);
        }
#pragma unroll
        for (int off = 16; off; off >>= 1) p += __shfl_xor(p, off, 32);
        Ku = p;
        cpt++;
        if (cpt % 50 == 1) {
            int chk = cpt / 50;  // 0..9
            float e = fabsf(v_r * Ku - bval);   // uniform across the row's 32 lanes
            e += __shfl_xor(e, 32, 64);         // pair the wave's two rows
            if ((tid & 63) == 0) redw[tid >> 6] = e;
            __syncthreads();
            if (tid == 0) {                      // ONE atomic per block
                float s = 0.0f;
#pragma unroll
                for (int i = 0; i < 16; i++) s += redw[i];
                atomicAdd(&err_buf[chk], s);
            }
            gbarN(bar_cnt, bar_gen, lg, NBLK_L);
            err = err_buf[chk];
        }
    }

    // ---- S = sum(max(u_i K_ij v_j, 1e-6)) ----
    float pS = 0.0f;
    for (int k8 = lane; k8 < D / 8; k8 += 32) {
        uint4 kw = *(const uint4*)&Kr[k8 * 8];
        float4 v0 = vb4[k8 * 2], v1 = vb4[k8 * 2 + 1];
        pS += fmaxf(u_r * bflo(kw.x) * v0.x, 1e-6f) + fmaxf(u_r * bfhi(kw.x) * v0.y, 1e-6f) +
              fmaxf(u_r * bflo(kw.y) * v0.z, 1e-6f) + fmaxf(u_r * bfhi(kw.y) * v0.w, 1e-6f) +
              fmaxf(u_r * bflo(kw.z) * v1.x, 1e-6f) + fmaxf(u_r * bfhi(kw.z) * v1.y, 1e-6f) +
              fmaxf(u_r * bflo(kw.w) * v1.z, 1e-6f) + fmaxf(u_r * bfhi(kw.w) * v1.w, 1e-6f);
    }
#pragma unroll
    for (int off = 16; off; off >>= 1) pS += __shfl_xor(pS, off, 32);
    pS += __shfl_xor(pS, 32, 64);
    if ((tid & 63) == 0) redw[tid >> 6] = pS;
    __syncthreads();
    if (tid == 0) {
        float s = 0.0f;
#pragma unroll
        for (int i = 0; i < 16; i++) s += redw[i];
        atomicAdd(S_buf, s);
    }
    // build 1/rsum LDS table while waiting on S (4M rcp -> 2048)
    if (tid < D / 4) {
        float4 rv = ((const float4*)rsum)[tid];
        ((float4*)rbuf)[tid] = make_float4(1.0f / rv.x, 1.0f / rv.y, 1.0f / rv.z, 1.0f / rv.w);
    }
    gbarN(bar_cnt, bar_gen, lg, NBLK_L);  // S complete grid-wide (also covers rbuf via syncthreads)

    // ---- KL epilogue: 1 log/elem typical (logq skipped by wave clamp-vote), logS hoisted ----
    const float LOGT = -13.815511f;  // log(1e-6)
    float logS = __logf(S_buf[0]);
    float invr_i = rbuf[row];
    float pkl = 0.0f, psum = 0.0f;
    const float4* pc4 = (const float4*)(Pc + (size_t)row * D);
    const float4* rb4 = (const float4*)rbuf;
    for (int k = lane; k < D / 4; k += 32) {
        uint2 kw = *(const uint2*)&Kr[k * 4];
        float K0 = bflo(kw.x), K1 = bfhi(kw.x), K2 = bflo(kw.y), K3 = bfhi(kw.y);
        float4 pc = pc4[k];
        float4 ir = rb4[k];
        float4 b = vb4[k];
        float P0 = pc.x * 0.5f * (invr_i + ir.x);
        float P1 = pc.y * 0.5f * (invr_i + ir.y);
        float P2 = pc.z * 0.5f * (invr_i + ir.z);
        float P3 = pc.w * 0.5f * (invr_i + ir.w);
        float w0 = u_r * K0 * b.x;
        float w1 = u_r * K1 * b.y;
        float w2 = u_r * K2 * b.z;
        float w3 = u_r * K3 * b.w;
        float lq0, lq1, lq2, lq3;
        if (__any(fmaxf(fmaxf(w0, w1), fmaxf(w2, w3)) > 1e-6f)) {
            lq0 = __logf(fmaxf(w0, 1e-6f));
            lq1 = __logf(fmaxf(w1, 1e-6f));
            lq2 = __logf(fmaxf(w2, 1e-6f));
            lq3 = __logf(fmaxf(w3, 1e-6f));
        } else {
            lq0 = lq1 = lq2 = lq3 = LOGT;  // whole wave clamped: no transcendentals
        }
        pkl += P0 * (__logf(P0) - lq0);
        pkl += P1 * (__logf(P1) - lq1);
        pkl += P2 * (__logf(P2) - lq2);
        pkl += P3 * (__logf(P3) - lq3);
        psum += (P0 + P1) + (P2 + P3);
    }
    pkl = fmaf(logS, psum, pkl);  // fold Σ P*logS once per lane
#pragma unroll
    for (int off = 16; off; off >>= 1) pkl += __shfl_xor(pkl, off, 32);
    pkl += __shfl_xor(pkl, 32, 64);
    if ((tid & 63) == 0) redw[tid >> 6] = pkl;
    __syncthreads();
    if (tid == 0) {
        float s = 0.0f;
#pragma unroll
        for (int i = 0; i < 16; i++) s += redw[i];
        atomicAdd(out, s);  // out memset to 0 by harness per replay
    }
}

// ========== FALLBACK: r2-proven monolithic sinkhorn (256 blocks, flat gbar) ==========
__global__ __launch_bounds__(256) void sinkhorn_kernel(
    const float* __restrict__ Kg, const float* __restrict__ Pc,
    float* __restrict__ rsum,
    float* __restrict__ u_g, float* __restrict__ v_g,
    float* __restrict__ err_buf, float* __restrict__ S_buf, float* __restrict__ kl_buf,
    unsigned* __restrict__ bar_cnt, unsigned* __restrict__ bar_gen,
    float* __restrict__ out) {
    extern __shared__ float KrowF[];  // RPB_F * D floats = 64 KB
    int tid = threadIdx.x;
    int blk = blockIdx.x;
    int r = tid >> 5;
    int lane = tid & 31;
    int row = blk * RPB_F + r;
    unsigned lg = 0;

    {
        const float4* src = (const float4*)(Kg + (size_t)blk * RPB_F * D);
        float4* dst = (float4*)KrowF;
        for (int i = tid; i < RPB_F * D / 4; i += 256) dst[i] = src[i];
    }
    {
        const float4* p4 = (const float4*)(Pc + (size_t)row * D);
        float s = 0.0f;
        for (int k = lane; k < D / 4; k += 32) {
            float4 v = p4[k];
            s += (v.x + v.y) + (v.z + v.w);
        }
#pragma unroll
        for (int off = 16; off; off >>= 1) s += __shfl_xor(s, off, 32);
        if (lane == 0) rsum[row] = s;
    }
    __syncthreads();

    const float bval = 1.0f / (float)D;
    const float aval = 1.0f / (float)D;
    const float4* Kr4 = (const float4*)(KrowF + r * D);
    const float4* v4 = (const float4*)v_g;
    const float4* u4 = (const float4*)u_g;

    float p = 0.0f;
    for (int k = lane; k < D / 4; k += 32) {
        float4 a = Kr4[k];
        p += (a.x + a.y) + (a.z + a.w);
    }
#pragma unroll
    for (int off = 16; off; off >>= 1) p += __shfl_xor(p, off, 32);
    float Ku = p;

    float err = 1.0f;
    int cpt = 0;
    float v_r = 0.0f, u_r = 0.0f;
    while (err > STOPTHR && cpt < 500) {
        v_r = bval / (Ku + EPSV);
        if (lane == 0) v_g[row] = v_r;
        gbarN(bar_cnt, bar_gen, lg, NBLK_F);
        p = 0.0f;
        for (int k = lane; k < D / 4; k += 32) {
            float4 a = Kr4[k];
            float4 b = v4[k];
            p = fmaf(a.x, b.x, p); p = fmaf(a.y, b.y, p);
            p = fmaf(a.z, b.z, p); p = fmaf(a.w, b.w, p);
        }
#pragma unroll
        for (int off = 16; off; off >>= 1) p += __shfl_xor(p, off, 32);
        u_r = aval / (p + EPSV);
        if (lane == 0) u_g[row] = u_r;
        gbarN(bar_cnt, bar_gen, lg, NBLK_F);
        p = 0.0f;
        for (int k = lane; k < D / 4; k += 32) {
            float4 a = Kr4[k];
            float4 b = u4[k];
            p = fmaf(a.x, b.x, p); p = fmaf(a.y, b.y, p);
            p = fmaf(a.z, b.z, p); p = fmaf(a.w, b.w, p);
        }
#pragma unroll
        for (int off = 16; off; off >>= 1) p += __shfl_xor(p, off, 32);
        Ku = p;
        cpt++;
        if (cpt % 50 == 1) {
            int chk = cpt / 50;
            float e = fabsf(v_r * Ku - bval);
            e += __shfl_xor(e, 32, 64);
            if ((tid & 63) == 0) atomicAdd(&err_buf[chk], e);
            gbarN(bar_cnt, bar_gen, lg, NBLK_F);
            err = err_buf[chk];
        }
    }

    float pS = 0.0f;
    for (int k = lane; k < D / 4; k += 32) {
        float4 a = Kr4[k];
        float4 b = v4[k];
        pS += fmaxf(u_r * a.x * b.x, 1e-6f) + fmaxf(u_r * a.y * b.y, 1e-6f) +
              fmaxf(u_r * a.z * b.z, 1e-6f) + fmaxf(u_r * a.w * b.w, 1e-6f);
    }
#pragma unroll
    for (int off = 16; off; off >>= 1) pS += __shfl_xor(pS, off, 32);
    pS += __shfl_xor(pS, 32, 64);
    if ((tid & 63) == 0) atomicAdd(S_buf, pS);
    gbarN(bar_cnt, bar_gen, lg, NBLK_F);
    float logS = __logf(S_buf[0]);

    float invr_i = 1.0f / rsum[row];
    float pkl = 0.0f;
    const float4* Pc4 = (const float4*)(Pc + (size_t)row * D);
    const float4* rs4 = (const float4*)rsum;
    for (int k = lane; k < D / 4; k += 32) {
        float4 a = Kr4[k];
        float4 b = v4[k];
        float4 pc = Pc4[k];
        float4 rs = rs4[k];
        float P0 = pc.x * 0.5f * (invr_i + 1.0f / rs.x);
        float P1 = pc.y * 0.5f * (invr_i + 1.0f / rs.y);
        float P2 = pc.z * 0.5f * (invr_i + 1.0f / rs.z);
        float P3 = pc.w * 0.5f * (invr_i + 1.0f / rs.w);
        float q0 = fmaxf(u_r * a.x * b.x, 1e-6f);
        float q1 = fmaxf(u_r * a.y * b.y, 1e-6f);
        float q2 = fmaxf(u_r * a.z * b.z, 1e-6f);
        float q3 = fmaxf(u_r * a.w * b.w, 1e-6f);
        pkl += P0 * (__logf(P0) - __logf(q0) + logS);
        pkl += P1 * (__logf(P1) - __logf(q1) + logS);
        pkl += P2 * (__logf(P2) - __logf(q2) + logS);
        pkl += P3 * (__logf(P3) - __logf(q3) + logS);
    }
#pragma unroll
    for (int off = 16; off; off >>= 1) pkl += __shfl_xor(pkl, off, 32);
    pkl += __shfl_xor(pkl, 32, 64);
    if ((tid & 63) == 0) atomicAdd(kl_buf, pkl);
    gbarN(bar_cnt, bar_gen, lg, NBLK_F);
    if (blk == 0 && tid == 0) out[0] = kl_buf[0];
}

extern "C" void kernel_launch(void* const* d_in, const int* in_sizes, int n_in,
                              void* d_out, int out_size, void* d_ws, size_t ws_size,
                              hipStream_t stream) {
    const float* theta = (const float*)d_in[0];
    const float* emb = (const float*)d_in[1];
    float* out = (float*)d_out;

    char* ws = (char*)d_ws;
    float* Kg = (float*)ws;                      // 16 MiB
    float* Pc = (float*)(ws + (1u << 24));       // 16 MiB
    char* tail = ws + (1u << 25);
    float* sq   = (float*)(tail);
    float* nrm  = (float*)(tail + 8192);
    float* rsum = (float*)(tail + 16384);
    float* u_g  = (float*)(tail + 24576);
    float* v_g  = (float*)(tail + 32768);
    float* err_buf = (float*)(tail + 40960);     // 10 floats
    float* S_buf   = (float*)(tail + 41216);
    float* kl_buf  = (float*)(tail + 41472);
    unsigned* bar_cnt  = (unsigned*)(tail + 41728);
    unsigned* bar_gen  = (unsigned*)(tail + 41984);
    float* vslab = (float*)(tail + 65536);       // dense 2048 f32 = 8 KiB
    float* uslab = (float*)(tail + 65536 + 8192);
    unsigned short* Yth = (unsigned short*)(tail + 131072);               // 1 MiB used
    unsigned short* Yem = (unsigned short*)(tail + 131072 + (1u << 21));  // 1 MiB used

    // one-time opt-in for 128 KB dynamic LDS on the loop kernel; fall back if refused
    static int attr_ok = -1;
    if (attr_ok < 0) {
        attr_ok = (hipFuncSetAttribute((const void*)sinkhorn_loop_kernel,
                                       hipFuncAttributeMaxDynamicSharedMemorySize,
                                       RPB_L * D * sizeof(unsigned short)) == hipSuccess) ? 1 : 0;
    }

    rowstats_kernel<<<D, 256, 0, stream>>>(theta, emb, sq, nrm, Yth, Yem,
                                           err_buf, S_buf, kl_buf, bar_cnt, bar_gen);
    gram_mfma_kernel<<<dim3(16, 16, 2), 256, 0, stream>>>(Yth, Yem, sq, nrm, Kg, Pc);

    if (attr_ok == 1) {
        sinkhorn_loop_kernel<<<NBLK_L, 1024, RPB_L * D * sizeof(unsigned short), stream>>>(
            Kg, Pc, rsum, uslab, vslab, err_buf, S_buf, bar_cnt, bar_gen, out);
    } else {
        sinkhorn_kernel<<<NBLK_F, 256, RPB_F * D * sizeof(float), stream>>>(
            Kg, Pc, rsum, u_g, v_g, err_buf, S_buf, kl_buf, bar_cnt, bar_gen, out);
    }
}

// Round 12
// 110.425 us; speedup vs baseline: 1.2061x; 1.0671x over previous
//
#include <hip/hip_runtime.h>
#include <math.h>

#define D 2048
#define F 256
#define ALPHA 0.005f
#define STOPTHR 0.005f
#define EPSV 1e-16f

// fast path: 64 blocks x 1024 threads, 32 rows/block, bf16 K in 128KB dynamic LDS
#define NBLK_L 64
#define RPB_L 32
// fallback path (r2-proven structure): 256 blocks x 256 threads, 8 rows/block
#define NBLK_F 256
#define RPB_F 8

typedef __bf16 bf16x8 __attribute__((ext_vector_type(8)));
typedef float f32x4 __attribute__((ext_vector_type(4)));
typedef unsigned short u16x8 __attribute__((ext_vector_type(8)));

__device__ __forceinline__ unsigned short f2bf(float f) {
    unsigned u = __float_as_uint(f);
    unsigned r = (u + 0x7FFFu + ((u >> 16) & 1u)) >> 16;  // RNE
    return (unsigned short)r;
}
__device__ __forceinline__ float bf2f(unsigned short b) {
    return __uint_as_float(((unsigned)b) << 16);
}
__device__ __forceinline__ float bflo(unsigned w) { return __uint_as_float(w << 16); }
__device__ __forceinline__ float bfhi(unsigned w) { return __uint_as_float(w & 0xFFFF0000u); }

// ---- flat central grid barrier (r0-r8 proven; r5 distributed / r9 tree both regressed) ----
__device__ __forceinline__ void gbarN(unsigned* cnt, unsigned* gen, unsigned& lg, int N) {
    __syncthreads();
    if (threadIdx.x == 0) {
        unsigned g = lg;
        unsigned a = __hip_atomic_fetch_add(cnt, 1u, __ATOMIC_ACQ_REL, __HIP_MEMORY_SCOPE_AGENT);
        if (a == (unsigned)(N - 1)) {
            __hip_atomic_store(cnt, 0u, __ATOMIC_RELAXED, __HIP_MEMORY_SCOPE_AGENT);
            __hip_atomic_store(gen, g + 1u, __ATOMIC_RELEASE, __HIP_MEMORY_SCOPE_AGENT);
        } else {
            while ((int)(__hip_atomic_load(gen, __ATOMIC_ACQUIRE, __HIP_MEMORY_SCOPE_AGENT) - (g + 1u)) < 0) {}
        }
    }
    __syncthreads();
    lg++;
}

// ---------------- row stats + plain-bf16 cast + flag/accum init ----------------
__global__ void rowstats_kernel(const float* __restrict__ theta,
                                const float* __restrict__ emb,
                                float* __restrict__ sq, float* __restrict__ nrm,
                                unsigned short* __restrict__ Yth,
                                unsigned short* __restrict__ Yem,
                                float* __restrict__ err_buf, float* __restrict__ S_buf,
                                float* __restrict__ kl_buf,
                                unsigned* __restrict__ bar_cnt, unsigned* __restrict__ bar_gen) {
    if (blockIdx.x == 0) {
        int t0 = threadIdx.x;
        if (t0 < 10) err_buf[t0] = 0.0f;
        else if (t0 == 10) S_buf[0] = 0.0f;
        else if (t0 == 11) kl_buf[0] = 0.0f;
        else if (t0 == 12) *bar_cnt = 0u;
        else if (t0 == 13) *bar_gen = 0u;
    }
    int row = blockIdx.x;
    int t = threadIdx.x;  // 256 threads == F
    float tv = theta[row * F + t];
    float ev = emb[row * F + t];

    Yth[row * F + t] = f2bf(tv);
    Yem[row * F + t] = f2bf(ev);

    float s1 = tv * tv, s2 = ev * ev;
    for (int off = 32; off; off >>= 1) {
        s1 += __shfl_down(s1, off, 64);
        s2 += __shfl_down(s2, off, 64);
    }
    __shared__ float w1[4], w2[4];
    int wid = t >> 6;
    if ((t & 63) == 0) { w1[wid] = s1; w2[wid] = s2; }
    __syncthreads();
    if (t == 0) {
        sq[row]  = w1[0] + w1[1] + w1[2] + w1[3];
        nrm[row] = sqrtf(w2[0] + w2[1] + w2[2] + w2[3]);
    }
}

// ---------------- Gram via bf16 MFMA, K=256; OUTPUTS bf16 (r12: halves L3 streams) --------
// bf16 Kg: identical effective precision to the loop's previous stage-convert.
// bf16 Pc: rsum err ~0.01%, logP abs err ~0.004 vs threshold 312.
#define GBK 64
#define GPAD 72

__global__ __launch_bounds__(256) void gram_mfma_kernel(
    const unsigned short* __restrict__ Yth, const unsigned short* __restrict__ Yem,
    const float* __restrict__ sq, const float* __restrict__ nrm,
    unsigned short* __restrict__ Kg, unsigned short* __restrict__ Pc) {
    int z = blockIdx.z;
    const unsigned short* Y = z ? Yem : Yth;
    int brow = blockIdx.y * 128;
    int bcol = blockIdx.x * 128;
    __shared__ __align__(16) unsigned short PA[128 * GPAD];
    __shared__ __align__(16) unsigned short PB[128 * GPAD];
    int tid = threadIdx.x;
    int wid = tid >> 6, lane = tid & 63;
    int wr = wid >> 1, wc = wid & 1;
    int lr = lane & 15;
    int lk = (lane >> 4) * 8;

    f32x4 acc[4][4] = {};

    for (int k0 = 0; k0 < F; k0 += GBK) {
        __syncthreads();
#pragma unroll
        for (int q = 0; q < 4; q++) {
            int c = tid + q * 256;
            int rw = c >> 3, ch = (c & 7) * 8;
            *(float4*)&PA[rw * GPAD + ch] =
                *(const float4*)&Y[(size_t)(brow + rw) * F + k0 + ch];
            *(float4*)&PB[rw * GPAD + ch] =
                *(const float4*)&Y[(size_t)(bcol + rw) * F + k0 + ch];
        }
        __syncthreads();
#pragma unroll
        for (int ks = 0; ks < 2; ks++) {
            bf16x8 af[4], bff[4];
#pragma unroll
            for (int m = 0; m < 4; m++)
                af[m] = *(const bf16x8*)&PA[(wr * 64 + m * 16 + lr) * GPAD + ks * 32 + lk];
#pragma unroll
            for (int n = 0; n < 4; n++)
                bff[n] = *(const bf16x8*)&PB[(wc * 64 + n * 16 + lr) * GPAD + ks * 32 + lk];
#pragma unroll
            for (int m = 0; m < 4; m++)
#pragma unroll
                for (int n = 0; n < 4; n++)
                    acc[m][n] = __builtin_amdgcn_mfma_f32_16x16x32_bf16(
                        af[m], bff[n], acc[m][n], 0, 0, 0);
        }
    }

    int ib = brow + wr * 64;
    int jb = bcol + wc * 64;
    int rr = (lane >> 4) * 4;
    if (z == 0) {
        float sqi[4][4];
#pragma unroll
        for (int m = 0; m < 4; m++)
#pragma unroll
            for (int q = 0; q < 4; q++) sqi[m][q] = sq[ib + m * 16 + rr + q];
#pragma unroll
        for (int n = 0; n < 4; n++) {
            int j = jb + n * 16 + lr;
            float sqj = sq[j];
#pragma unroll
            for (int m = 0; m < 4; m++)
#pragma unroll
                for (int q = 0; q < 4; q++) {
                    int i = ib + m * 16 + rr + q;
                    float cc = fmaxf(sqi[m][q] + sqj - 2.0f * acc[m][n][q], 0.0f);
                    Kg[(size_t)i * D + j] = f2bf(__expf(-ALPHA * cc));
                }
        }
    } else {
        float nri[4][4];
#pragma unroll
        for (int m = 0; m < 4; m++)
#pragma unroll
            for (int q = 0; q < 4; q++) nri[m][q] = nrm[ib + m * 16 + rr + q];
#pragma unroll
        for (int n = 0; n < 4; n++) {
            int j = jb + n * 16 + lr;
            float nrj = nrm[j];
#pragma unroll
            for (int m = 0; m < 4; m++)
#pragma unroll
                for (int q = 0; q < 4; q++) {
                    int i = ib + m * 16 + rr + q;
                    Pc[(size_t)i * D + j] = f2bf(acc[m][n][q] / (nri[m][q] * nrj + EPSV));
                }
        }
    }
}

// ========== FAST PATH: 64 blocks x 1024 threads, 32 rows/block, bf16 K, flat gbar ==========
__global__ __launch_bounds__(1024) void sinkhorn_loop_kernel(
    const unsigned short* __restrict__ Kg, const unsigned short* __restrict__ Pc,
    float* __restrict__ rsum,
    float* __restrict__ uslab, float* __restrict__ vslab,
    float* __restrict__ err_buf, float* __restrict__ S_buf,
    unsigned* __restrict__ bar_cnt, unsigned* __restrict__ bar_gen,
    float* __restrict__ out) {
    extern __shared__ unsigned short Krow_bf[];  // RPB_L * D bf16 = 128 KB dynamic
    __shared__ float vbuf[D], ubuf[D], rbuf[D];  // 24 KB static (rbuf = 1/rsum table)
    __shared__ float redw[16];                   // per-wave scratch for block reduce
    int tid = threadIdx.x;
    int blk = blockIdx.x;
    int r = tid >> 5;        // 0..31
    int lane = tid & 31;
    int row = blk * RPB_L + r;
    unsigned lg = 0;

    // stage 32 K-rows: straight bf16 copy (8 MB grid-wide, no convert)
    {
        const uint4* src = (const uint4*)(Kg + (size_t)blk * RPB_L * D);
        uint4* dst = (uint4*)Krow_bf;
        for (int i = tid; i < RPB_L * D / 8; i += 1024) dst[i] = src[i];
    }
    // rsum of bf16 Pc for this block's 32 rows
    {
        const uint4* p4 = (const uint4*)(Pc + (size_t)row * D);
        float s = 0.0f;
        for (int k8 = lane; k8 < D / 8; k8 += 32) {
            uint4 w = p4[k8];
            s += bflo(w.x) + bfhi(w.x) + bflo(w.y) + bfhi(w.y) +
                 bflo(w.z) + bfhi(w.z) + bflo(w.w) + bfhi(w.w);
        }
#pragma unroll
        for (int off = 16; off; off >>= 1) s += __shfl_xor(s, off, 32);
        if (lane == 0) rsum[row] = s;
    }
    __syncthreads();

    const float bval = 1.0f / (float)D;
    const float aval = 1.0f / (float)D;
    const unsigned short* Kr = &Krow_bf[r * D];

    // Ku for u0 = ones: row sum (from bf16)
    float p = 0.0f;
    for (int k8 = lane; k8 < D / 8; k8 += 32) {
        uint4 kw = *(const uint4*)&Kr[k8 * 8];
        p += bflo(kw.x) + bfhi(kw.x) + bflo(kw.y) + bfhi(kw.y) +
             bflo(kw.z) + bfhi(kw.z) + bflo(kw.w) + bfhi(kw.w);
    }
#pragma unroll
    for (int off = 16; off; off >>= 1) p += __shfl_xor(p, off, 32);
    float Ku = p;

    const float4* vsl4 = (const float4*)vslab;
    const float4* usl4 = (const float4*)uslab;
    float4* vb4w = (float4*)vbuf;
    float4* ub4w = (float4*)ubuf;
    const float4* vb4 = (const float4*)vbuf;
    const float4* ub4 = (const float4*)ubuf;

    float err = 1.0f;
    int cpt = 0;
    float v_r = 0.0f, u_r = 0.0f;
    while (err > STOPTHR && cpt < 500) {
        v_r = bval / (Ku + EPSV);
        if (lane == 0) vslab[row] = v_r;
        gbarN(bar_cnt, bar_gen, lg, NBLK_L);
        if (tid < D / 4) vb4w[tid] = vsl4[tid];  // bounce v -> dense LDS
        __syncthreads();
        p = 0.0f;
        for (int k8 = lane; k8 < D / 8; k8 += 32) {
            uint4 kw = *(const uint4*)&Kr[k8 * 8];
            float4 v0 = vb4[k8 * 2], v1 = vb4[k8 * 2 + 1];
            p = fmaf(bflo(kw.x), v0.x, p); p = fmaf(bfhi(kw.x), v0.y, p);
            p = fmaf(bflo(kw.y), v0.z, p); p = fmaf(bfhi(kw.y), v0.w, p);
            p = fmaf(bflo(kw.z), v1.x, p); p = fmaf(bfhi(kw.z), v1.y, p);
            p = fmaf(bflo(kw.w), v1.z, p); p = fmaf(bfhi(kw.w), v1.w, p);
        }
#pragma unroll
        for (int off = 16; off; off >>= 1) p += __shfl_xor(p, off, 32);
        u_r = aval / (p + EPSV);
        if (lane == 0) uslab[row] = u_r;
        gbarN(bar_cnt, bar_gen, lg, NBLK_L);
        if (tid < D / 4) ub4w[tid] = usl4[tid];  // bounce u -> dense LDS
        __syncthreads();
        p = 0.0f;
        for (int k8 = lane; k8 < D / 8; k8 += 32) {
            uint4 kw = *(const uint4*)&Kr[k8 * 8];
            float4 u0 = ub4[k8 * 2], u1 = ub4[k8 * 2 + 1];
            p = fmaf(bflo(kw.x), u0.x, p); p = fmaf(bfhi(kw.x), u0.y, p);
            p = fmaf(bflo(kw.y), u0.z, p); p = fmaf(bfhi(kw.y), u0.w, p);
            p = fmaf(bflo(kw.z), u1.x, p); p = fmaf(bfhi(kw.z), u1.y, p);
            p = fmaf(bflo(kw.w), u1.z, p); p = fmaf(bfhi(kw.w), u1.w, p);
        }
#pragma unroll
        for (int off = 16; off; off >>= 1) p += __shfl_xor(p, off, 32);
        Ku = p;
        cpt++;
        if (cpt % 50 == 1) {
            int chk = cpt / 50;  // 0..9
            float e = fabsf(v_r * Ku - bval);   // uniform across the row's 32 lanes
            e += __shfl_xor(e, 32, 64);         // pair the wave's two rows
            if ((tid & 63) == 0) redw[tid >> 6] = e;
            __syncthreads();
            if (tid == 0) {                      // ONE atomic per block
                float s = 0.0f;
#pragma unroll
                for (int i = 0; i < 16; i++) s += redw[i];
                atomicAdd(&err_buf[chk], s);
            }
            gbarN(bar_cnt, bar_gen, lg, NBLK_L);
            err = err_buf[chk];
        }
    }

    // ---- S = sum(max(u_i K_ij v_j, 1e-6)) ----
    float pS = 0.0f;
    for (int k8 = lane; k8 < D / 8; k8 += 32) {
        uint4 kw = *(const uint4*)&Kr[k8 * 8];
        float4 v0 = vb4[k8 * 2], v1 = vb4[k8 * 2 + 1];
        pS += fmaxf(u_r * bflo(kw.x) * v0.x, 1e-6f) + fmaxf(u_r * bfhi(kw.x) * v0.y, 1e-6f) +
              fmaxf(u_r * bflo(kw.y) * v0.z, 1e-6f) + fmaxf(u_r * bfhi(kw.y) * v0.w, 1e-6f) +
              fmaxf(u_r * bflo(kw.z) * v1.x, 1e-6f) + fmaxf(u_r * bfhi(kw.z) * v1.y, 1e-6f) +
              fmaxf(u_r * bflo(kw.w) * v1.z, 1e-6f) + fmaxf(u_r * bfhi(kw.w) * v1.w, 1e-6f);
    }
#pragma unroll
    for (int off = 16; off; off >>= 1) pS += __shfl_xor(pS, off, 32);
    pS += __shfl_xor(pS, 32, 64);
    if ((tid & 63) == 0) redw[tid >> 6] = pS;
    __syncthreads();
    if (tid == 0) {
        float s = 0.0f;
#pragma unroll
        for (int i = 0; i < 16; i++) s += redw[i];
        atomicAdd(S_buf, s);
    }
    // build 1/rsum LDS table while waiting on S (4M rcp -> 2048)
    if (tid < D / 4) {
        float4 rv = ((const float4*)rsum)[tid];
        ((float4*)rbuf)[tid] = make_float4(1.0f / rv.x, 1.0f / rv.y, 1.0f / rv.z, 1.0f / rv.w);
    }
    gbarN(bar_cnt, bar_gen, lg, NBLK_L);  // S complete grid-wide

    // ---- KL epilogue: clamp-vote logq skip, rcp table, logS folded; bf16 Pc stream ----
    const float LOGT = -13.815511f;  // log(1e-6)
    float logS = __logf(S_buf[0]);
    float invr_i = rbuf[row];
    float pkl = 0.0f, psum = 0.0f;
    const uint2* pc2 = (const uint2*)(Pc + (size_t)row * D);  // 4 bf16 per uint2
    const float4* rb4 = (const float4*)rbuf;
    for (int k = lane; k < D / 4; k += 32) {
        uint2 kw = *(const uint2*)&Kr[k * 4];
        float K0 = bflo(kw.x), K1 = bfhi(kw.x), K2 = bflo(kw.y), K3 = bfhi(kw.y);
        uint2 pw = pc2[k];
        float pc0 = bflo(pw.x), pc1 = bfhi(pw.x), pc2v = bflo(pw.y), pc3 = bfhi(pw.y);
        float4 ir = rb4[k];
        float4 b = vb4[k];
        float P0 = pc0 * 0.5f * (invr_i + ir.x);
        float P1 = pc1 * 0.5f * (invr_i + ir.y);
        float P2 = pc2v * 0.5f * (invr_i + ir.z);
        float P3 = pc3 * 0.5f * (invr_i + ir.w);
        float w0 = u_r * K0 * b.x;
        float w1 = u_r * K1 * b.y;
        float w2 = u_r * K2 * b.z;
        float w3 = u_r * K3 * b.w;
        float lq0, lq1, lq2, lq3;
        if (__any(fmaxf(fmaxf(w0, w1), fmaxf(w2, w3)) > 1e-6f)) {
            lq0 = __logf(fmaxf(w0, 1e-6f));
            lq1 = __logf(fmaxf(w1, 1e-6f));
            lq2 = __logf(fmaxf(w2, 1e-6f));
            lq3 = __logf(fmaxf(w3, 1e-6f));
        } else {
            lq0 = lq1 = lq2 = lq3 = LOGT;  // whole wave clamped: no transcendentals
        }
        pkl += P0 * (__logf(P0) - lq0);
        pkl += P1 * (__logf(P1) - lq1);
        pkl += P2 * (__logf(P2) - lq2);
        pkl += P3 * (__logf(P3) - lq3);
        psum += (P0 + P1) + (P2 + P3);
    }
    pkl = fmaf(logS, psum, pkl);  // fold Σ P*logS once per lane
#pragma unroll
    for (int off = 16; off; off >>= 1) pkl += __shfl_xor(pkl, off, 32);
    pkl += __shfl_xor(pkl, 32, 64);
    if ((tid & 63) == 0) redw[tid >> 6] = pkl;
    __syncthreads();
    if (tid == 0) {
        float s = 0.0f;
#pragma unroll
        for (int i = 0; i < 16; i++) s += redw[i];
        atomicAdd(out, s);  // out memset to 0 by harness per replay
    }
}

// ========== FALLBACK: monolithic sinkhorn (256 blocks, flat gbar), bf16 inputs ==========
__global__ __launch_bounds__(256) void sinkhorn_kernel(
    const unsigned short* __restrict__ Kg, const unsigned short* __restrict__ Pc,
    float* __restrict__ rsum,
    float* __restrict__ u_g, float* __restrict__ v_g,
    float* __restrict__ err_buf, float* __restrict__ S_buf, float* __restrict__ kl_buf,
    unsigned* __restrict__ bar_cnt, unsigned* __restrict__ bar_gen,
    float* __restrict__ out) {
    extern __shared__ float KrowF[];  // RPB_F * D floats = 64 KB
    int tid = threadIdx.x;
    int blk = blockIdx.x;
    int r = tid >> 5;
    int lane = tid & 31;
    int row = blk * RPB_F + r;
    unsigned lg = 0;

    {   // stage bf16 Kg -> f32 LDS
        const uint4* src = (const uint4*)(Kg + (size_t)blk * RPB_F * D);
        for (int i = tid; i < RPB_F * D / 8; i += 256) {
            uint4 w = src[i];
            float4 lo = make_float4(bflo(w.x), bfhi(w.x), bflo(w.y), bfhi(w.y));
            float4 hi = make_float4(bflo(w.z), bfhi(w.z), bflo(w.w), bfhi(w.w));
            ((float4*)KrowF)[i * 2] = lo;
            ((float4*)KrowF)[i * 2 + 1] = hi;
        }
    }
    {
        const uint4* p4 = (const uint4*)(Pc + (size_t)row * D);
        float s = 0.0f;
        for (int k8 = lane; k8 < D / 8; k8 += 32) {
            uint4 w = p4[k8];
            s += bflo(w.x) + bfhi(w.x) + bflo(w.y) + bfhi(w.y) +
                 bflo(w.z) + bfhi(w.z) + bflo(w.w) + bfhi(w.w);
        }
#pragma unroll
        for (int off = 16; off; off >>= 1) s += __shfl_xor(s, off, 32);
        if (lane == 0) rsum[row] = s;
    }
    __syncthreads();

    const float bval = 1.0f / (float)D;
    const float aval = 1.0f / (float)D;
    const float4* Kr4 = (const float4*)(KrowF + r * D);
    const float4* v4 = (const float4*)v_g;
    const float4* u4 = (const float4*)u_g;

    float p = 0.0f;
    for (int k = lane; k < D / 4; k += 32) {
        float4 a = Kr4[k];
        p += (a.x + a.y) + (a.z + a.w);
    }
#pragma unroll
    for (int off = 16; off; off >>= 1) p += __shfl_xor(p, off, 32);
    float Ku = p;

    float err = 1.0f;
    int cpt = 0;
    float v_r = 0.0f, u_r = 0.0f;
    while (err > STOPTHR && cpt < 500) {
        v_r = bval / (Ku + EPSV);
        if (lane == 0) v_g[row] = v_r;
        gbarN(bar_cnt, bar_gen, lg, NBLK_F);
        p = 0.0f;
        for (int k = lane; k < D / 4; k += 32) {
            float4 a = Kr4[k];
            float4 b = v4[k];
            p = fmaf(a.x, b.x, p); p = fmaf(a.y, b.y, p);
            p = fmaf(a.z, b.z, p); p = fmaf(a.w, b.w, p);
        }
#pragma unroll
        for (int off = 16; off; off >>= 1) p += __shfl_xor(p, off, 32);
        u_r = aval / (p + EPSV);
        if (lane == 0) u_g[row] = u_r;
        gbarN(bar_cnt, bar_gen, lg, NBLK_F);
        p = 0.0f;
        for (int k = lane; k < D / 4; k += 32) {
            float4 a = Kr4[k];
            float4 b = u4[k];
            p = fmaf(a.x, b.x, p); p = fmaf(a.y, b.y, p);
            p = fmaf(a.z, b.z, p); p = fmaf(a.w, b.w, p);
        }
#pragma unroll
        for (int off = 16; off; off >>= 1) p += __shfl_xor(p, off, 32);
        Ku = p;
        cpt++;
        if (cpt % 50 == 1) {
            int chk = cpt / 50;
            float e = fabsf(v_r * Ku - bval);
            e += __shfl_xor(e, 32, 64);
            if ((tid & 63) == 0) atomicAdd(&err_buf[chk], e);
            gbarN(bar_cnt, bar_gen, lg, NBLK_F);
            err = err_buf[chk];
        }
    }

    float pS = 0.0f;
    for (int k = lane; k < D / 4; k += 32) {
        float4 a = Kr4[k];
        float4 b = v4[k];
        pS += fmaxf(u_r * a.x * b.x, 1e-6f) + fmaxf(u_r * a.y * b.y, 1e-6f) +
              fmaxf(u_r * a.z * b.z, 1e-6f) + fmaxf(u_r * a.w * b.w, 1e-6f);
    }
#pragma unroll
    for (int off = 16; off; off >>= 1) pS += __shfl_xor(pS, off, 32);
    pS += __shfl_xor(pS, 32, 64);
    if ((tid & 63) == 0) atomicAdd(S_buf, pS);
    gbarN(bar_cnt, bar_gen, lg, NBLK_F);
    float logS = __logf(S_buf[0]);

    float invr_i = 1.0f / rsum[row];
    float pkl = 0.0f;
    const uint2* pc2 = (const uint2*)(Pc + (size_t)row * D);
    const float4* rs4 = (const float4*)rsum;
    const float4* v4b = (const float4*)v_g;
    for (int k = lane; k < D / 4; k += 32) {
        float4 a = Kr4[k];
        float4 b = v4b[k];
        uint2 pw = pc2[k];
        float pc0 = bflo(pw.x), pc1 = bfhi(pw.x), pc2v = bflo(pw.y), pc3 = bfhi(pw.y);
        float4 rs = rs4[k];
        float P0 = pc0 * 0.5f * (invr_i + 1.0f / rs.x);
        float P1 = pc1 * 0.5f * (invr_i + 1.0f / rs.y);
        float P2 = pc2v * 0.5f * (invr_i + 1.0f / rs.z);
        float P3 = pc3 * 0.5f * (invr_i + 1.0f / rs.w);
        float q0 = fmaxf(u_r * a.x * b.x, 1e-6f);
        float q1 = fmaxf(u_r * a.y * b.y, 1e-6f);
        float q2 = fmaxf(u_r * a.z * b.z, 1e-6f);
        float q3 = fmaxf(u_r * a.w * b.w, 1e-6f);
        pkl += P0 * (__logf(P0) - __logf(q0) + logS);
        pkl += P1 * (__logf(P1) - __logf(q1) + logS);
        pkl += P2 * (__logf(P2) - __logf(q2) + logS);
        pkl += P3 * (__logf(P3) - __logf(q3) + logS);
    }
#pragma unroll
    for (int off = 16; off; off >>= 1) pkl += __shfl_xor(pkl, off, 32);
    pkl += __shfl_xor(pkl, 32, 64);
    if ((tid & 63) == 0) atomicAdd(kl_buf, pkl);
    gbarN(bar_cnt, bar_gen, lg, NBLK_F);
    if (blk == 0 && tid == 0) out[0] = kl_buf[0];
}

extern "C" void kernel_launch(void* const* d_in, const int* in_sizes, int n_in,
                              void* d_out, int out_size, void* d_ws, size_t ws_size,
                              hipStream_t stream) {
    const float* theta = (const float*)d_in[0];
    const float* emb = (const float*)d_in[1];
    float* out = (float*)d_out;

    char* ws = (char*)d_ws;
    unsigned short* Kg = (unsigned short*)ws;               // 8 MiB bf16
    unsigned short* Pc = (unsigned short*)(ws + (1u << 23)); // 8 MiB bf16
    char* tail = ws + (1u << 24);
    float* sq   = (float*)(tail);
    float* nrm  = (float*)(tail + 8192);
    float* rsum = (float*)(tail + 16384);
    float* u_g  = (float*)(tail + 24576);
    float* v_g  = (float*)(tail + 32768);
    float* err_buf = (float*)(tail + 40960);     // 10 floats
    float* S_buf   = (float*)(tail + 41216);
    float* kl_buf  = (float*)(tail + 41472);
    unsigned* bar_cnt  = (unsigned*)(tail + 41728);
    unsigned* bar_gen  = (unsigned*)(tail + 41984);
    float* vslab = (float*)(tail + 65536);       // dense 2048 f32 = 8 KiB
    float* uslab = (float*)(tail + 65536 + 8192);
    unsigned short* Yth = (unsigned short*)(tail + 131072);               // 1 MiB used
    unsigned short* Yem = (unsigned short*)(tail + 131072 + (1u << 21));  // 1 MiB used

    // one-time opt-in for 128 KB dynamic LDS on the loop kernel; fall back if refused
    static int attr_ok = -1;
    if (attr_ok < 0) {
        attr_ok = (hipFuncSetAttribute((const void*)sinkhorn_loop_kernel,
                                       hipFuncAttributeMaxDynamicSharedMemorySize,
                                       RPB_L * D * sizeof(unsigned short)) == hipSuccess) ? 1 : 0;
    }

    rowstats_kernel<<<D, 256, 0, stream>>>(theta, emb, sq, nrm, Yth, Yem,
                                           err_buf, S_buf, kl_buf, bar_cnt, bar_gen);
    gram_mfma_kernel<<<dim3(16, 16, 2), 256, 0, stream>>>(Yth, Yem, sq, nrm, Kg, Pc);

    if (attr_ok == 1) {
        sinkhorn_loop_kernel<<<NBLK_L, 1024, RPB_L * D * sizeof(unsigned short), stream>>>(
            Kg, Pc, rsum, uslab, vslab, err_buf, S_buf, bar_cnt, bar_gen, out);
    } else {
        sinkhorn_kernel<<<NBLK_F, 256, RPB_F * D * sizeof(float), stream>>>(
            Kg, Pc, rsum, u_g, v_g, err_buf, S_buf, kl_buf, bar_cnt, bar_gen, out);
    }
}